// Round 1
// baseline (2190.749 us; speedup 1.0000x reference)
//
#include <hip/hip_runtime.h>
#include <math.h>

#define NB 64
#define NN 197
#define NC 768
#define NH 12
#define ND 64
#define KCB 50
#define NM (NN-1)                    // 196
#define BNROWS (NB*NN)               // 12608
#define SZ ((size_t)NB*NH*NN*ND)     // 9,682,944
#define ABN ((size_t)NB*NH*NN*NN)    // 29,805,312

typedef unsigned short u16;
typedef unsigned int u32;
typedef unsigned long long u64;

__device__ __forceinline__ u16 f2bf(float x) {
  u32 u = __float_as_uint(x);
  u = (u + 0x7fffu + ((u >> 16) & 1u)) >> 16;
  return (u16)u;
}
__device__ __forceinline__ float bf2f(u16 b) { return __uint_as_float(((u32)b) << 16); }
__device__ __forceinline__ u32 packbf(float a, float b) {
  return (u32)f2bf(a) | ((u32)f2bf(b) << 16);
}

__device__ __forceinline__ float brMax(float v, float* red, int tid) {
  red[tid] = v;
  __syncthreads();
  if (tid < 64) {
    float a = fmaxf(fmaxf(red[tid], red[tid+64]), fmaxf(red[tid+128], red[tid+192]));
    #pragma unroll
    for (int off = 32; off > 0; off >>= 1) a = fmaxf(a, __shfl_down(a, off));
    if (tid == 0) red[256] = a;
  }
  __syncthreads();
  return red[256];
}
__device__ __forceinline__ float brSum(float v, float* red, int tid) {
  red[tid] = v;
  __syncthreads();
  if (tid < 64) {
    float a = red[tid] + red[tid+64] + red[tid+128] + red[tid+192];
    #pragma unroll
    for (int off = 32; off > 0; off >>= 1) a += __shfl_down(a, off);
    if (tid == 0) red[256] = a;
  }
  __syncthreads();
  return red[256];
}

// ---------------- GEMM: C[r,o] = sum_c A[r,c]*W[o,c]  (A: BNROWS x 768 rows) ----------------
// MODE 0: qkv (W 2304 rows) -> scatter q/k fp32, v bf16 into [B,H,N,D]
// MODE 1: proj (W 768 rows) -> d_out[r*768+o] + bias
template<int MODE>
__global__ __launch_bounds__(256)
void gemm_kernel(const float* __restrict__ A, const float* __restrict__ W,
                 float* __restrict__ qb_, float* __restrict__ kb_, u16* __restrict__ vb_,
                 const float* __restrict__ bias, float* __restrict__ dout)
{
  __shared__ __align__(16) float As[16*128];
  __shared__ __align__(16) float Bs[16*128];
  const int tid = threadIdx.x;
  const int tx = tid & 15, ty = tid >> 4;
  const int row0 = blockIdx.x * 128, col0 = blockIdx.y * 128;
  const int lr = tid >> 2, lc = tid & 3;

  float acc[8][8];
  #pragma unroll
  for (int i = 0; i < 8; ++i)
    #pragma unroll
    for (int j = 0; j < 8; ++j) acc[i][j] = 0.f;

  for (int kt = 0; kt < 48; ++kt) {
    #pragma unroll
    for (int half = 0; half < 2; ++half) {
      int r = row0 + half*64 + lr;
      float4 av = make_float4(0.f, 0.f, 0.f, 0.f);
      if (r < BNROWS) av = *(const float4*)(A + (size_t)r*768 + kt*16 + lc*4);
      As[(lc*4+0)*128 + half*64 + lr] = av.x;
      As[(lc*4+1)*128 + half*64 + lr] = av.y;
      As[(lc*4+2)*128 + half*64 + lr] = av.z;
      As[(lc*4+3)*128 + half*64 + lr] = av.w;
      int wr = col0 + half*64 + lr;
      float4 bv = *(const float4*)(W + (size_t)wr*768 + kt*16 + lc*4);
      Bs[(lc*4+0)*128 + half*64 + lr] = bv.x;
      Bs[(lc*4+1)*128 + half*64 + lr] = bv.y;
      Bs[(lc*4+2)*128 + half*64 + lr] = bv.z;
      Bs[(lc*4+3)*128 + half*64 + lr] = bv.w;
    }
    __syncthreads();
    #pragma unroll
    for (int kk = 0; kk < 16; ++kk) {
      float4 a0 = *(const float4*)&As[kk*128 + ty*4];
      float4 a1 = *(const float4*)&As[kk*128 + 64 + ty*4];
      float4 b0 = *(const float4*)&Bs[kk*128 + tx*4];
      float4 b1 = *(const float4*)&Bs[kk*128 + 64 + tx*4];
      float a_[8] = {a0.x,a0.y,a0.z,a0.w,a1.x,a1.y,a1.z,a1.w};
      float b_[8] = {b0.x,b0.y,b0.z,b0.w,b1.x,b1.y,b1.z,b1.w};
      #pragma unroll
      for (int i = 0; i < 8; ++i)
        #pragma unroll
        for (int j = 0; j < 8; ++j) acc[i][j] = fmaf(a_[i], b_[j], acc[i][j]);
    }
    __syncthreads();
  }

  #pragma unroll
  for (int i = 0; i < 8; ++i) {
    int r = row0 + (i >> 2)*64 + ty*4 + (i & 3);
    if (r >= BNROWS) continue;
    if constexpr (MODE == 0) {
      int b_ = r / 197, n_ = r - b_*197;
      #pragma unroll
      for (int jq = 0; jq < 2; ++jq) {
        int o0 = col0 + jq*64 + tx*4;
        int t = o0 / 768, rem = o0 - t*768;
        int hh = rem >> 6, dd = rem & 63;
        size_t dst = ((size_t)(b_*12 + hh)*197 + n_)*64 + dd;
        float4 v4 = make_float4(acc[i][jq*4+0], acc[i][jq*4+1], acc[i][jq*4+2], acc[i][jq*4+3]);
        if (t == 0)      *(float4*)(qb_ + dst) = v4;
        else if (t == 1) *(float4*)(kb_ + dst) = v4;
        else {
          uint2 p = make_uint2(packbf(v4.x, v4.y), packbf(v4.z, v4.w));
          *(uint2*)(vb_ + dst) = p;
        }
      }
    } else {
      #pragma unroll
      for (int jq = 0; jq < 2; ++jq) {
        int o0 = col0 + jq*64 + tx*4;
        float4 bb = *(const float4*)(bias + o0);
        float4 v4 = make_float4(acc[i][jq*4+0]+bb.x, acc[i][jq*4+1]+bb.y,
                                acc[i][jq*4+2]+bb.z, acc[i][jq*4+3]+bb.w);
        *(float4*)(dout + (size_t)r*768 + o0) = v4;
      }
    }
  }
}

// ---------------- Quantize q/k tokens 1..196, write bf16 cat buffers + MSE partials ----------
__global__ __launch_bounds__(256)
void quant_kernel(const float* __restrict__ x, const float* __restrict__ qkv_w,
                  const float* __restrict__ qbuf, const float* __restrict__ kbuf,
                  const float* __restrict__ qe, const float* __restrict__ ke,
                  u16* __restrict__ cq, u16* __restrict__ ck, float* __restrict__ pq)
{
  __shared__ __align__(16) float Qt[64*197];   // transposed [i][tok], pad 197
  __shared__ __align__(16) float El[KCB*66];   // codebook, pad 66
  __shared__ double e2d[KCB];
  __shared__ int idxb[NM];
  __shared__ float wred[4];
  const int tid = threadIdx.x;
  const int bh = blockIdx.x;
  const int which = blockIdx.y;
  const int b_ = bh / 12, h_ = bh - b_*12;
  const float* feat = which ? kbuf : qbuf;
  const float* emb  = which ? ke : qe;
  u16* dst = which ? ck : cq;
  const size_t base = (size_t)bh * (197*64);

  for (int idx = tid; idx < KCB*64; idx += 256) {
    int kk = idx >> 6, i = idx & 63;
    El[kk*66 + i] = emb[h_*(KCB*64) + idx];
  }
  for (int idx = tid; idx < NM*64; idx += 256) {
    int mm = idx >> 6, i = idx & 63;
    Qt[i*197 + mm] = feat[base + (size_t)(mm+1)*64 + i];
  }
  // cls passthrough (token 0)
  if (tid >= 64 && tid < 128) {
    int i = tid - 64;
    dst[base + i] = f2bf(feat[base + i]);
  }
  __syncthreads();
  if (tid < KCB) {
    double s = 0.0;
    for (int i = 0; i < 64; ++i) { double e = (double)El[tid*66 + i]; s += e*e; }
    e2d[tid] = s;
  }
  __syncthreads();

  const int tok = tid;
  double d1 = 1e300, d2 = 1e300;
  int bidx = 0;
  if (tok < NM) {
    for (int kc = 0; kc < 5; ++kc) {
      double dot[10];
      #pragma unroll
      for (int u = 0; u < 10; ++u) dot[u] = 0.0;
      for (int j = 0; j < 32; ++j) {
        double fx = (double)Qt[(2*j)*197 + tok];
        double fy = (double)Qt[(2*j+1)*197 + tok];
        #pragma unroll
        for (int u = 0; u < 10; ++u) {
          float2 ev = *(const float2*)&El[(kc*10+u)*66 + 2*j];
          dot[u] = fma(fx, (double)ev.x, dot[u]);
          dot[u] = fma(fy, (double)ev.y, dot[u]);
        }
      }
      #pragma unroll
      for (int u = 0; u < 10; ++u) {
        int kk = kc*10 + u;
        double dist = e2d[kk] - 2.0*dot[u];
        if (dist < d1) { d2 = d1; d1 = dist; bidx = kk; }
        else if (dist < d2) d2 = dist;
      }
    }
  }
  // exact fp64 rescue for near-ties (wave-cooperative)
  const int lane = tid & 63;
  u64 flags = __ballot(tok < NM && (d2 - d1) < 1e-3);
  while (flags) {
    int src = __ffsll(flags) - 1;
    flags &= flags - 1;
    int ftok = (tid & ~63) + src;
    int mrow = 1 + ftok;
    const float* xrow = x + (size_t)(b_*197 + mrow)*768;
    const float* wrow = qkv_w + (size_t)(which*768 + h_*64 + lane)*768;
    double qd = 0.0;
    for (int c = 0; c < 768; ++c) qd = fma((double)xrow[c], (double)wrow[c], qd);
    double bb = 1e300; int bi = 0;
    for (int kk = 0; kk < KCB; ++kk) {
      double df = qd - (double)El[kk*66 + lane];
      double sq = df*df;
      #pragma unroll
      for (int off = 32; off > 0; off >>= 1) sq += __shfl_xor(sq, off);
      if (sq < bb) { bb = sq; bi = kk; }
    }
    if (lane == src) bidx = bi;
  }
  if (tok < NM) idxb[tok] = bidx;
  __syncthreads();

  float msel = 0.f;
  for (int idx = tid; idx < NM*64; idx += 256) {
    int mm = idx >> 6, i = idx & 63;
    float ev = El[idxb[mm]*66 + i];
    float qv = Qt[i*197 + mm];
    float df = ev - qv;
    msel = fmaf(df, df, msel);
    dst[base + (size_t)(mm+1)*64 + i] = f2bf(ev);
  }
  #pragma unroll
  for (int off = 32; off > 0; off >>= 1) msel += __shfl_down(msel, off);
  if (lane == 0) wred[tid >> 6] = msel;
  __syncthreads();
  if (tid == 0) pq[which*768 + bh] = wred[0]+wred[1]+wred[2]+wred[3];
}

// ---------------- attn = softmax(q k^T / 8); write bf16 attn + sum(a*log a) partial ----------
__global__ __launch_bounds__(256)
void attn_kernel(const float* __restrict__ qbuf, const float* __restrict__ kbuf,
                 u16* __restrict__ abf, float* __restrict__ pa)
{
  __shared__ u32 Kl[197*32];
  __shared__ __align__(16) float qb[64];
  __shared__ float red[257];
  const int tid = threadIdx.x;
  const int bh = blockIdx.x;
  const size_t base = (size_t)bh * (197*64);
  for (int idx = tid; idx < 197*32; idx += 256) {
    int mm = idx >> 5, j = idx & 31;
    float2 kv = *(const float2*)(kbuf + base + mm*64 + 2*j);
    Kl[mm*32 + (j ^ (mm & 31))] = packbf(kv.x, kv.y);
  }
  __syncthreads();
  float aloga = 0.f;
  for (int n = 0; n < 197; ++n) {
    if (tid < 64) qb[tid] = qbuf[base + n*64 + tid];
    __syncthreads();
    float logit = -INFINITY;
    if (tid < 197) {
      float dot = 0.f;
      #pragma unroll
      for (int j = 0; j < 32; ++j) {
        u32 u = Kl[tid*32 + (j ^ (tid & 31))];
        float2 qv = *(const float2*)&qb[2*j];
        dot = fmaf(qv.x, __uint_as_float(u << 16), dot);
        dot = fmaf(qv.y, __uint_as_float(u & 0xffff0000u), dot);
      }
      logit = dot * 0.125f;
    }
    float mx = brMax(logit, red, tid);
    float ex = (tid < 197) ? __expf(logit - mx) : 0.f;
    float sm = brSum(ex, red, tid);
    if (tid < 197) {
      float a = ex / sm;
      abf[((size_t)bh*197 + n)*197 + tid] = f2bf(a);
      aloga += a * __logf(a);
    }
  }
  float tot = brSum(aloga, red, tid);
  if (tid == 0) pa[bh] = tot;
}

// ---------------- quant_attn softmax + PV + sum(a*qa) partial + attn-out -------------------
__global__ __launch_bounds__(256)
void qattn_kernel(const u16* __restrict__ cq, const u16* __restrict__ ck,
                  const u16* __restrict__ vb, const u16* __restrict__ abf,
                  float* __restrict__ ao, float* __restrict__ pb)
{
  __shared__ u32 CKl[197*32];
  __shared__ u16 Vl[197*64];
  __shared__ __align__(16) float qb[64];
  __shared__ float qa[197];
  __shared__ float red[257];
  const int tid = threadIdx.x;
  const int bh = blockIdx.x;
  const int b_ = bh / 12, h_ = bh - b_*12;
  const size_t base = (size_t)bh * (197*64);
  const u32* ck32 = (const u32*)ck;
  const u32* vb32 = (const u32*)vb;
  const size_t base2 = base >> 1;
  for (int idx = tid; idx < 197*32; idx += 256) {
    int mm = idx >> 5, j = idx & 31;
    CKl[mm*32 + (j ^ (mm & 31))] = ck32[base2 + idx];
    ((u32*)Vl)[idx] = vb32[base2 + idx];
  }
  __syncthreads();
  float aqa = 0.f;
  for (int n = 0; n < 197; ++n) {
    if (tid < 64) qb[tid] = bf2f(cq[base + n*64 + tid]);
    __syncthreads();
    float logit = -INFINITY;
    if (tid < 197) {
      float dot = 0.f;
      #pragma unroll
      for (int j = 0; j < 32; ++j) {
        u32 u = CKl[tid*32 + (j ^ (tid & 31))];
        float2 qv = *(const float2*)&qb[2*j];
        dot = fmaf(qv.x, __uint_as_float(u << 16), dot);
        dot = fmaf(qv.y, __uint_as_float(u & 0xffff0000u), dot);
      }
      logit = dot * 0.125f;
    }
    float mx = brMax(logit, red, tid);
    float ex = (tid < 197) ? __expf(logit - mx) : 0.f;
    float sm = brSum(ex, red, tid);
    if (tid < 197) {
      float qv_ = ex / sm;
      qa[tid] = qv_;
      aqa = fmaf(bf2f(abf[((size_t)bh*197 + n)*197 + tid]), qv_, aqa);
    }
    __syncthreads();
    const int dd = tid & 63, grp = tid >> 6;
    float acc = 0.f;
    for (int mm = grp; mm < 197; mm += 4)
      acc = fmaf(qa[mm], bf2f(Vl[mm*64 + dd]), acc);
    red[tid] = acc;
    __syncthreads();
    if (tid < 64) {
      float o = red[tid] + red[tid+64] + red[tid+128] + red[tid+192];
      ao[((size_t)(b_*197 + n))*768 + h_*64 + tid] = o;
    }
    __syncthreads();
  }
  float tot = brSum(aqa, red, tid);
  if (tid == 0) pb[bh] = tot;
}

// ---------------- deterministic loss finalize ----------------
__global__ __launch_bounds__(256)
void finalize_kernel(const float* __restrict__ pq, const float* __restrict__ pa,
                     const float* __restrict__ pb, float* __restrict__ dout)
{
  __shared__ double red[256];
  const int tid = threadIdx.x;
  double s0 = 0.0, s1 = 0.0;
  for (int i = tid; i < 1536; i += 256) s0 += (double)pq[i];
  for (int i = tid; i < 768; i += 256) s1 += (double)pa[i] - (double)pb[i];
  red[tid] = s0; __syncthreads();
  for (int off = 128; off > 0; off >>= 1) { if (tid < off) red[tid] += red[tid+off]; __syncthreads(); }
  double mse = red[0];
  __syncthreads();
  red[tid] = s1; __syncthreads();
  for (int off = 128; off > 0; off >>= 1) { if (tid < off) red[tid] += red[tid+off]; __syncthreads(); }
  double kl = red[0];
  if (tid == 0) dout[SZ] = (float)(mse / 9633792.0 + kl / 29805312.0);
}

extern "C" void kernel_launch(void* const* d_in, const int* in_sizes, int n_in,
                              void* d_out, int out_size, void* d_ws, size_t ws_size,
                              hipStream_t stream)
{
  const float* x      = (const float*)d_in[0];
  const float* qkv_w  = (const float*)d_in[1];
  const float* proj_w = (const float*)d_in[2];
  const float* proj_b = (const float*)d_in[3];
  const float* qe     = (const float*)d_in[4];
  const float* ke     = (const float*)d_in[5];
  float* out = (float*)d_out;

  float* ws  = (float*)d_ws;
  float* qb_ = ws;                       // SZ fp32 (reused as attn-out later)
  float* kb_ = ws + SZ;                  // SZ fp32
  u16*   vb_ = (u16*)(ws + 2*SZ);        // SZ bf16
  u16*   cq_ = (u16*)(ws + 2*SZ + SZ/2); // SZ bf16
  u16*   ck_ = (u16*)(ws + 3*SZ);        // SZ bf16
  u16*   abf_= (u16*)(ws + 3*SZ + SZ/2); // ABN bf16
  float* pq_ = ws + 3*SZ + SZ/2 + ABN/2; // 1536
  float* pa_ = pq_ + 1536;               // 768
  float* pb_ = pa_ + 768;                // 768
  float* ao_ = qb_;                      // alias: q dead after attn_kernel

  dim3 blk(256);
  gemm_kernel<0><<<dim3(99, 18), blk, 0, stream>>>(x, qkv_w, qb_, kb_, vb_, nullptr, nullptr);
  quant_kernel<<<dim3(768, 2), blk, 0, stream>>>(x, qkv_w, qb_, kb_, qe, ke, cq_, ck_, pq_);
  attn_kernel<<<dim3(768), blk, 0, stream>>>(qb_, kb_, abf_, pa_);
  qattn_kernel<<<dim3(768), blk, 0, stream>>>(cq_, ck_, vb_, abf_, ao_, pb_);
  gemm_kernel<1><<<dim3(99, 6), blk, 0, stream>>>(ao_, proj_w, nullptr, nullptr, nullptr, proj_b, out);
  finalize_kernel<<<dim3(1), blk, 0, stream>>>(pq_, pa_, pb_, out);
}

// Round 2
// 1247.725 us; speedup vs baseline: 1.7558x; 1.7558x over previous
//
#include <hip/hip_runtime.h>
#include <math.h>

#define NB 64
#define NN 197
#define NC 768
#define NH 12
#define ND 64
#define KCB 50
#define NM (NN-1)                    // 196
#define BNROWS (NB*NN)               // 12608
#define SZ ((size_t)NB*NH*NN*ND)     // 9,682,944
#define ABN ((size_t)NB*NH*NN*NN)    // 29,805,312

typedef unsigned short u16;
typedef unsigned int u32;
typedef unsigned long long u64;
typedef _Float16 h2 __attribute__((ext_vector_type(2)));

__device__ __forceinline__ u16 f2bf(float x) {
  u32 u = __float_as_uint(x);
  u = (u + 0x7fffu + ((u >> 16) & 1u)) >> 16;
  return (u16)u;
}
__device__ __forceinline__ u16 f2h(float x) {
  _Float16 h = (_Float16)x;
  return *(u16*)&h;
}
__device__ __forceinline__ u32 packh2(float a, float b) {
  h2 v = { (_Float16)a, (_Float16)b };
  return *(u32*)&v;
}
__device__ __forceinline__ h2 as_h2(u32 u) { return *(h2*)&u; }

#if __has_builtin(__builtin_amdgcn_fdot2)
__device__ __forceinline__ float dot2(h2 a, h2 b, float c) {
  return __builtin_amdgcn_fdot2(a, b, c, false);
}
#else
__device__ __forceinline__ float dot2(h2 a, h2 b, float c) {
  return fmaf((float)a.x, (float)b.x, fmaf((float)a.y, (float)b.y, c));
}
#endif

__device__ __forceinline__ float brSum(float v, float* red, int tid) {
  red[tid] = v;
  __syncthreads();
  if (tid < 64) {
    float a = red[tid] + red[tid+64] + red[tid+128] + red[tid+192];
    #pragma unroll
    for (int off = 32; off > 0; off >>= 1) a += __shfl_down(a, off);
    if (tid == 0) red[256] = a;
  }
  __syncthreads();
  return red[256];
}

// ---------------- GEMM: C[r,o] = sum_c A[r,c]*W[o,c]  (A: BNROWS x 768 rows) ----------------
// MODE 0: qkv (W 2304 rows) -> scatter q/k fp32, v f16 into [B,H,N,D]
// MODE 1: proj (W 768 rows) -> d_out[r*768+o] + bias
template<int MODE>
__global__ __launch_bounds__(256)
void gemm_kernel(const float* __restrict__ A, const float* __restrict__ W,
                 float* __restrict__ qb_, float* __restrict__ kb_, u16* __restrict__ vb_,
                 const float* __restrict__ bias, float* __restrict__ dout)
{
  __shared__ __align__(16) float As[16*128];
  __shared__ __align__(16) float Bs[16*128];
  const int tid = threadIdx.x;
  const int tx = tid & 15, ty = tid >> 4;
  const int row0 = blockIdx.x * 128, col0 = blockIdx.y * 128;
  const int lr = tid >> 2, lc = tid & 3;

  float acc[8][8];
  #pragma unroll
  for (int i = 0; i < 8; ++i)
    #pragma unroll
    for (int j = 0; j < 8; ++j) acc[i][j] = 0.f;

  for (int kt = 0; kt < 48; ++kt) {
    #pragma unroll
    for (int half = 0; half < 2; ++half) {
      int r = row0 + half*64 + lr;
      float4 av = make_float4(0.f, 0.f, 0.f, 0.f);
      if (r < BNROWS) av = *(const float4*)(A + (size_t)r*768 + kt*16 + lc*4);
      As[(lc*4+0)*128 + half*64 + lr] = av.x;
      As[(lc*4+1)*128 + half*64 + lr] = av.y;
      As[(lc*4+2)*128 + half*64 + lr] = av.z;
      As[(lc*4+3)*128 + half*64 + lr] = av.w;
      int wr = col0 + half*64 + lr;
      float4 bv = *(const float4*)(W + (size_t)wr*768 + kt*16 + lc*4);
      Bs[(lc*4+0)*128 + half*64 + lr] = bv.x;
      Bs[(lc*4+1)*128 + half*64 + lr] = bv.y;
      Bs[(lc*4+2)*128 + half*64 + lr] = bv.z;
      Bs[(lc*4+3)*128 + half*64 + lr] = bv.w;
    }
    __syncthreads();
    #pragma unroll
    for (int kk = 0; kk < 16; ++kk) {
      float4 a0 = *(const float4*)&As[kk*128 + ty*4];
      float4 a1 = *(const float4*)&As[kk*128 + 64 + ty*4];
      float4 b0 = *(const float4*)&Bs[kk*128 + tx*4];
      float4 b1 = *(const float4*)&Bs[kk*128 + 64 + tx*4];
      float a_[8] = {a0.x,a0.y,a0.z,a0.w,a1.x,a1.y,a1.z,a1.w};
      float b_[8] = {b0.x,b0.y,b0.z,b0.w,b1.x,b1.y,b1.z,b1.w};
      #pragma unroll
      for (int i = 0; i < 8; ++i)
        #pragma unroll
        for (int j = 0; j < 8; ++j) acc[i][j] = fmaf(a_[i], b_[j], acc[i][j]);
    }
    __syncthreads();
  }

  #pragma unroll
  for (int i = 0; i < 8; ++i) {
    int r = row0 + (i >> 2)*64 + ty*4 + (i & 3);
    if (r >= BNROWS) continue;
    if constexpr (MODE == 0) {
      int b_ = r / 197, n_ = r - b_*197;
      #pragma unroll
      for (int jq = 0; jq < 2; ++jq) {
        int o0 = col0 + jq*64 + tx*4;
        int t = o0 / 768, rem = o0 - t*768;
        int hh = rem >> 6, dd = rem & 63;
        size_t dst = ((size_t)(b_*12 + hh)*197 + n_)*64 + dd;
        float4 v4 = make_float4(acc[i][jq*4+0], acc[i][jq*4+1], acc[i][jq*4+2], acc[i][jq*4+3]);
        if (t == 0)      *(float4*)(qb_ + dst) = v4;
        else if (t == 1) *(float4*)(kb_ + dst) = v4;
        else {
          uint2 p = make_uint2(packh2(v4.x, v4.y), packh2(v4.z, v4.w));
          *(uint2*)(vb_ + dst) = p;
        }
      }
    } else {
      #pragma unroll
      for (int jq = 0; jq < 2; ++jq) {
        int o0 = col0 + jq*64 + tx*4;
        float4 bb = *(const float4*)(bias + o0);
        float4 v4 = make_float4(acc[i][jq*4+0]+bb.x, acc[i][jq*4+1]+bb.y,
                                acc[i][jq*4+2]+bb.z, acc[i][jq*4+3]+bb.w);
        *(float4*)(dout + (size_t)r*768 + o0) = v4;
      }
    }
  }
}

// ---------------- Quantize q/k tokens 1..196, write f16 cat buffers + MSE partials ----------
__global__ __launch_bounds__(256)
void quant_kernel(const float* __restrict__ x, const float* __restrict__ qkv_w,
                  const float* __restrict__ qbuf, const float* __restrict__ kbuf,
                  const float* __restrict__ qe, const float* __restrict__ ke,
                  u16* __restrict__ cq, u16* __restrict__ ck, float* __restrict__ pq)
{
  __shared__ __align__(16) float Qt[64*197];   // transposed [i][tok], pad 197
  __shared__ __align__(16) float El[KCB*66];   // codebook, pad 66
  __shared__ double e2d[KCB];
  __shared__ int idxb[NM];
  __shared__ float wred[4];
  const int tid = threadIdx.x;
  const int bh = blockIdx.x;
  const int which = blockIdx.y;
  const int b_ = bh / 12, h_ = bh - b_*12;
  const float* feat = which ? kbuf : qbuf;
  const float* emb  = which ? ke : qe;
  u16* dst = which ? ck : cq;
  const size_t base = (size_t)bh * (197*64);

  for (int idx = tid; idx < KCB*64; idx += 256) {
    int kk = idx >> 6, i = idx & 63;
    El[kk*66 + i] = emb[h_*(KCB*64) + idx];
  }
  for (int idx = tid; idx < NM*64; idx += 256) {
    int mm = idx >> 6, i = idx & 63;
    Qt[i*197 + mm] = feat[base + (size_t)(mm+1)*64 + i];
  }
  // cls passthrough (token 0)
  if (tid >= 64 && tid < 128) {
    int i = tid - 64;
    dst[base + i] = f2h(feat[base + i]);
  }
  __syncthreads();
  if (tid < KCB) {
    double s = 0.0;
    for (int i = 0; i < 64; ++i) { double e = (double)El[tid*66 + i]; s += e*e; }
    e2d[tid] = s;
  }
  __syncthreads();

  const int tok = tid;
  double d1 = 1e300, d2 = 1e300;
  int bidx = 0;
  if (tok < NM) {
    for (int kc = 0; kc < 5; ++kc) {
      double dot[10];
      #pragma unroll
      for (int u = 0; u < 10; ++u) dot[u] = 0.0;
      for (int j = 0; j < 32; ++j) {
        double fx = (double)Qt[(2*j)*197 + tok];
        double fy = (double)Qt[(2*j+1)*197 + tok];
        #pragma unroll
        for (int u = 0; u < 10; ++u) {
          float2 ev = *(const float2*)&El[(kc*10+u)*66 + 2*j];
          dot[u] = fma(fx, (double)ev.x, dot[u]);
          dot[u] = fma(fy, (double)ev.y, dot[u]);
        }
      }
      #pragma unroll
      for (int u = 0; u < 10; ++u) {
        int kk = kc*10 + u;
        double dist = e2d[kk] - 2.0*dot[u];
        if (dist < d1) { d2 = d1; d1 = dist; bidx = kk; }
        else if (dist < d2) d2 = dist;
      }
    }
  }
  // exact fp64 rescue for near-ties (wave-cooperative)
  const int lane = tid & 63;
  u64 flags = __ballot(tok < NM && (d2 - d1) < 1e-3);
  while (flags) {
    int src = __ffsll(flags) - 1;
    flags &= flags - 1;
    int ftok = (tid & ~63) + src;
    int mrow = 1 + ftok;
    const float* xrow = x + (size_t)(b_*197 + mrow)*768;
    const float* wrow = qkv_w + (size_t)(which*768 + h_*64 + lane)*768;
    double qd = 0.0;
    for (int c = 0; c < 768; ++c) qd = fma((double)xrow[c], (double)wrow[c], qd);
    double bb = 1e300; int bi = 0;
    for (int kk = 0; kk < KCB; ++kk) {
      double df = qd - (double)El[kk*66 + lane];
      double sq = df*df;
      #pragma unroll
      for (int off = 32; off > 0; off >>= 1) sq += __shfl_xor(sq, off);
      if (sq < bb) { bb = sq; bi = kk; }
    }
    if (lane == src) bidx = bi;
  }
  if (tok < NM) idxb[tok] = bidx;
  __syncthreads();

  float msel = 0.f;
  for (int idx = tid; idx < NM*64; idx += 256) {
    int mm = idx >> 6, i = idx & 63;
    float ev = El[idxb[mm]*66 + i];
    float qv = Qt[i*197 + mm];
    float df = ev - qv;
    msel = fmaf(df, df, msel);
    dst[base + (size_t)(mm+1)*64 + i] = f2h(ev);
  }
  #pragma unroll
  for (int off = 32; off > 0; off >>= 1) msel += __shfl_down(msel, off);
  if (lane == 0) wred[tid >> 6] = msel;
  __syncthreads();
  if (tid == 0) pq[which*768 + bh] = wred[0]+wred[1]+wred[2]+wred[3];
}

// ---------------- fused: attn KL stats + quant_attn softmax + PV, no inner barriers --------
__global__ __launch_bounds__(256)
void fused_attn_kernel(const float* __restrict__ qbuf, const float* __restrict__ kbuf,
                       const u16* __restrict__ cq, const u16* __restrict__ ck,
                       const u16* __restrict__ vb,
                       float* __restrict__ ao, float* __restrict__ pkl)
{
  __shared__ __align__(16) u32 Kl[197*32];
  __shared__ __align__(16) u32 CKl[197*32];
  __shared__ __align__(16) u32 Vl[197*32];
  __shared__ float red[257];
  const int tid = threadIdx.x;
  const int bh = blockIdx.x;
  const int b_ = bh / 12, h_ = bh - b_*12;
  const size_t base = (size_t)bh * (197*64);
  const u32* ck32 = (const u32*)ck;
  const u32* vb32 = (const u32*)vb;
  const size_t base2 = base >> 1;

  // stage K (fp32->f16 pack), CK, V (already f16-packed)
  for (int idx = tid; idx < 197*32; idx += 256) {
    float2 kv = *(const float2*)(kbuf + base + 2*idx);
    Kl[idx] = packh2(kv.x, kv.y);
    CKl[idx] = ck32[base2 + idx];
    Vl[idx] = vb32[base2 + idx];
  }

  // per-thread rows in registers (packed f16)
  const int n = tid;
  u32 qr[32], cqr[32];
  if (n < 197) {
    #pragma unroll
    for (int j = 0; j < 16; ++j) {
      float4 qv = *(const float4*)(qbuf + base + (size_t)n*64 + j*4);
      qr[2*j]   = packh2(qv.x, qv.y);
      qr[2*j+1] = packh2(qv.z, qv.w);
    }
    const uint4* cp = (const uint4*)(cq + base + (size_t)n*64);
    #pragma unroll
    for (int j = 0; j < 8; ++j) {
      uint4 cu = cp[j];
      cqr[4*j] = cu.x; cqr[4*j+1] = cu.y; cqr[4*j+2] = cu.z; cqr[4*j+3] = cu.w;
    }
  }
  __syncthreads();

  float aM = -INFINITY, aS = 0.f, aT = 0.f;
  float qM = -INFINITY, qS = 0.f;
  float out[64];
  #pragma unroll
  for (int d = 0; d < 64; ++d) out[d] = 0.f;
  float cross = 0.f;

  if (n < 197) {
    // pass 1: online softmax stats for both attn (a) and quant_attn (qa)
    for (int m = 0; m < 197; ++m) {
      const u32* kp  = &Kl[m*32];
      const u32* ckp = &CKl[m*32];
      float ad0 = 0.f, ad1 = 0.f, qd0 = 0.f, qd1 = 0.f;
      #pragma unroll
      for (int j = 0; j < 32; j += 2) {
        ad0 = dot2(as_h2(qr[j]),    as_h2(kp[j]),    ad0);
        ad1 = dot2(as_h2(qr[j+1]),  as_h2(kp[j+1]),  ad1);
        qd0 = dot2(as_h2(cqr[j]),   as_h2(ckp[j]),   qd0);
        qd1 = dot2(as_h2(cqr[j+1]), as_h2(ckp[j+1]), qd1);
      }
      float l  = (ad0 + ad1) * 0.125f;
      float ql = (qd0 + qd1) * 0.125f;
      float nM = fmaxf(aM, l);
      float sc = __expf(aM - nM);
      float e  = __expf(l - nM);
      aS = fmaf(aS, sc, e);
      aT = fmaf(aT, sc, e * l);
      aM = nM;
      float nQ = fmaxf(qM, ql);
      float qsc = __expf(qM - nQ);
      float qe  = __expf(ql - nQ);
      qS = fmaf(qS, qsc, qe);
      qM = nQ;
    }
    float aSi = __frcp_rn(aS);
    float qSi = __frcp_rn(qS);
    // pass 2: recompute logits; accumulate cross = sum a*qa and PV
    for (int m = 0; m < 197; ++m) {
      const u32* kp  = &Kl[m*32];
      const u32* ckp = &CKl[m*32];
      float ad0 = 0.f, ad1 = 0.f, qd0 = 0.f, qd1 = 0.f;
      #pragma unroll
      for (int j = 0; j < 32; j += 2) {
        ad0 = dot2(as_h2(qr[j]),    as_h2(kp[j]),    ad0);
        ad1 = dot2(as_h2(qr[j+1]),  as_h2(kp[j+1]),  ad1);
        qd0 = dot2(as_h2(cqr[j]),   as_h2(ckp[j]),   qd0);
        qd1 = dot2(as_h2(cqr[j+1]), as_h2(ckp[j+1]), qd1);
      }
      float l  = (ad0 + ad1) * 0.125f;
      float ql = (qd0 + qd1) * 0.125f;
      float a  = __expf(l - aM) * aSi;
      float qa = __expf(ql - qM) * qSi;
      cross = fmaf(a, qa, cross);
      const u32* vp = &Vl[m*32];
      #pragma unroll
      for (int j = 0; j < 32; ++j) {
        h2 v = as_h2(vp[j]);
        out[2*j]   = fmaf((float)v.x, qa, out[2*j]);
        out[2*j+1] = fmaf((float)v.y, qa, out[2*j+1]);
      }
    }
    // write PV row
    float* orow = ao + ((size_t)(b_*197 + n))*768 + h_*64;
    #pragma unroll
    for (int j = 0; j < 16; ++j)
      *(float4*)(orow + j*4) = make_float4(out[4*j], out[4*j+1], out[4*j+2], out[4*j+3]);
  }

  float kln = 0.f;
  if (n < 197) kln = aT * __frcp_rn(aS) - aM - __logf(aS) - cross;
  float tot = brSum(kln, red, tid);
  if (tid == 0) pkl[bh] = tot;
}

// ---------------- deterministic loss finalize ----------------
__global__ __launch_bounds__(256)
void finalize_kernel(const float* __restrict__ pq, const float* __restrict__ pkl,
                     float* __restrict__ dout)
{
  __shared__ double red[256];
  const int tid = threadIdx.x;
  double s0 = 0.0, s1 = 0.0;
  for (int i = tid; i < 1536; i += 256) s0 += (double)pq[i];
  for (int i = tid; i < 768; i += 256) s1 += (double)pkl[i];
  red[tid] = s0; __syncthreads();
  for (int off = 128; off > 0; off >>= 1) { if (tid < off) red[tid] += red[tid+off]; __syncthreads(); }
  double mse = red[0];
  __syncthreads();
  red[tid] = s1; __syncthreads();
  for (int off = 128; off > 0; off >>= 1) { if (tid < off) red[tid] += red[tid+off]; __syncthreads(); }
  double kl = red[0];
  if (tid == 0) dout[SZ] = (float)(mse / 9633792.0 + kl / 29805312.0);
}

extern "C" void kernel_launch(void* const* d_in, const int* in_sizes, int n_in,
                              void* d_out, int out_size, void* d_ws, size_t ws_size,
                              hipStream_t stream)
{
  const float* x      = (const float*)d_in[0];
  const float* qkv_w  = (const float*)d_in[1];
  const float* proj_w = (const float*)d_in[2];
  const float* proj_b = (const float*)d_in[3];
  const float* qe     = (const float*)d_in[4];
  const float* ke     = (const float*)d_in[5];
  float* out = (float*)d_out;

  float* ws  = (float*)d_ws;
  float* qb_ = ws;                       // SZ fp32
  float* kb_ = ws + SZ;                  // SZ fp32
  float* ao_ = ws + 2*SZ;                // SZ fp32 (PV output)
  u16*   vb_ = (u16*)(ws + 3*SZ);        // SZ f16
  u16*   cq_ = vb_ + SZ;                 // SZ f16
  u16*   ck_ = cq_ + SZ;                 // SZ f16
  float* pq_ = (float*)(ck_ + SZ);       // 1536
  float* pkl_= pq_ + 1536;               // 768

  dim3 blk(256);
  gemm_kernel<0><<<dim3(99, 18), blk, 0, stream>>>(x, qkv_w, qb_, kb_, vb_, nullptr, nullptr);
  quant_kernel<<<dim3(768, 2), blk, 0, stream>>>(x, qkv_w, qb_, kb_, qe, ke, cq_, ck_, pq_);
  fused_attn_kernel<<<dim3(768), blk, 0, stream>>>(qb_, kb_, cq_, ck_, vb_, ao_, pkl_);
  gemm_kernel<1><<<dim3(99, 6), blk, 0, stream>>>(ao_, proj_w, nullptr, nullptr, nullptr, proj_b, out);
  finalize_kernel<<<dim3(1), blk, 0, stream>>>(pq_, pkl_, out);
}

// Round 3
// 783.256 us; speedup vs baseline: 2.7970x; 1.5930x over previous
//
#include <hip/hip_runtime.h>
#include <math.h>

#define NB 64
#define NN 197
#define NC 768
#define NH 12
#define ND 64
#define KCB 50
#define NM (NN-1)                    // 196
#define BNROWS (NB*NN)               // 12608
#define SZ ((size_t)NB*NH*NN*ND)     // 9,682,944
#define WQKV ((size_t)2304*768)      // 1,769,472
#define WPRJ ((size_t)768*768)       // 589,824

typedef unsigned short u16;
typedef unsigned int u32;
typedef unsigned long long u64;
typedef _Float16 h2 __attribute__((ext_vector_type(2)));
typedef _Float16 f16x8 __attribute__((ext_vector_type(8)));
typedef float f32x4 __attribute__((ext_vector_type(4)));

#define GLOAD16(gp, lp) __builtin_amdgcn_global_load_lds( \
    (const __attribute__((address_space(1))) void*)(gp),  \
    (__attribute__((address_space(3))) void*)(lp), 16, 0, 0)

__device__ __forceinline__ u16 f2h(float x) {
  _Float16 h = (_Float16)x;
  return *(u16*)&h;
}
__device__ __forceinline__ float h2f(u16 b) { _Float16 h = *(_Float16*)&b; return (float)h; }
__device__ __forceinline__ u32 packh2(float a, float b) {
  h2 v = { (_Float16)a, (_Float16)b };
  return *(u32*)&v;
}
__device__ __forceinline__ h2 as_h2(u32 u) { return *(h2*)&u; }
__device__ __forceinline__ float hres(float x) {  // residue after f16 rounding
  _Float16 h = (_Float16)x;
  return x - (float)h;
}

#if __has_builtin(__builtin_amdgcn_fdot2)
__device__ __forceinline__ float dot2(h2 a, h2 b, float c) {
  return __builtin_amdgcn_fdot2(a, b, c, false);
}
#else
__device__ __forceinline__ float dot2(h2 a, h2 b, float c) {
  return fmaf((float)a.x, (float)b.x, fmaf((float)a.y, (float)b.y, c));
}
#endif

__device__ __forceinline__ float brSum(float v, float* red, int tid) {
  red[tid] = v;
  __syncthreads();
  if (tid < 64) {
    float a = red[tid] + red[tid+64] + red[tid+128] + red[tid+192];
    #pragma unroll
    for (int off = 32; off > 0; off >>= 1) a += __shfl_down(a, off);
    if (tid == 0) red[256] = a;
  }
  __syncthreads();
  return red[256];
}

// ---------------- split fp32 -> f16 hi/lo planes ----------------
__global__ __launch_bounds__(256)
void split_kernel(const float* __restrict__ src, u16* __restrict__ hi,
                  u16* __restrict__ lo, int n4)
{
  int i = blockIdx.x*256 + threadIdx.x;
  if (i >= n4) return;
  float4 v = ((const float4*)src)[i];
  _Float16 h0 = (_Float16)v.x, h1 = (_Float16)v.y, h2_ = (_Float16)v.z, h3 = (_Float16)v.w;
  uint2 hv = make_uint2((u32)*(u16*)&h0 | ((u32)*(u16*)&h1 << 16),
                        (u32)*(u16*)&h2_ | ((u32)*(u16*)&h3 << 16));
  ((uint2*)hi)[i] = hv;
  _Float16 l0 = (_Float16)(v.x - (float)h0), l1 = (_Float16)(v.y - (float)h1);
  _Float16 l2 = (_Float16)(v.z - (float)h2_), l3 = (_Float16)(v.w - (float)h3);
  uint2 lv = make_uint2((u32)*(u16*)&l0 | ((u32)*(u16*)&l1 << 16),
                        (u32)*(u16*)&l2 | ((u32)*(u16*)&l3 << 16));
  ((uint2*)lo)[i] = lv;
}

// ---------------- MFMA GEMM, f16 split-3, C[r,o] = sum_c A[r,c]*W[o,c] ----------------
// 128x128 tile, BK=32, 4 waves, double-buffered LDS, global_load_lds staging.
// MODE 0: qkv (W 2304 rows) -> scatter q/k fp32, v f16
// MODE 1: proj (W 768 rows) -> d_out + bias
template<int MODE>
__global__ __launch_bounds__(256)
void gemm_mfma(const u16* __restrict__ Ah, const u16* __restrict__ Al,
               const u16* __restrict__ Wh, const u16* __restrict__ Wl,
               float* __restrict__ qb_, float* __restrict__ kb_, u16* __restrict__ vb_,
               const float* __restrict__ bias, float* __restrict__ dout)
{
  __shared__ u16 lds[2][4][4096];   // [buf][Ah,Al,Bh,Bl][128 rows x 32 f16], 64 KB
  const int tid = threadIdx.x;
  const int lane = tid & 63, w = tid >> 6;
  const int wm = w >> 1, wn = w & 1;
  const int row0 = blockIdx.x * 128, col0 = blockIdx.y * 128;

  f32x4 acc[4][4];
  #pragma unroll
  for (int mi = 0; mi < 4; ++mi)
    #pragma unroll
    for (int ni = 0; ni < 4; ++ni) acc[mi][ni] = (f32x4){0.f, 0.f, 0.f, 0.f};

  // staging: per wave 8 global_load_lds issues (A hi/lo + B hi/lo, 2x16 rows each)
  auto stage = [&](int buf, int kt) {
    const int c0 = kt * 32;
    #pragma unroll
    for (int j = 0; j < 2; ++j) {
      const int r0 = w*32 + j*16;
      const int lrow = r0 + (lane >> 2);
      const int slot = (lane & 3) ^ (lrow & 3);            // pre-swizzled global source
      int ar = row0 + lrow; if (ar > BNROWS-1) ar = BNROWS-1;
      const size_t ga = (size_t)ar * 768 + c0 + slot*8;
      const size_t gb = (size_t)(col0 + lrow) * 768 + c0 + slot*8;
      GLOAD16(Ah + ga, &lds[buf][0][r0*32]);
      GLOAD16(Al + ga, &lds[buf][1][r0*32]);
      GLOAD16(Wh + gb, &lds[buf][2][r0*32]);
      GLOAD16(Wl + gb, &lds[buf][3][r0*32]);
    }
  };

  auto compute = [&](int buf) {
    f16x8 ah[4], al[4], bh[4], bl[4];
    const int g = lane >> 4;
    #pragma unroll
    for (int mi = 0; mi < 4; ++mi) {
      int arow = wm*64 + mi*16 + (lane & 15);
      int off = arow*32 + ((g ^ (arow & 3)) << 3);
      ah[mi] = *(const f16x8*)&lds[buf][0][off];
      al[mi] = *(const f16x8*)&lds[buf][1][off];
    }
    #pragma unroll
    for (int ni = 0; ni < 4; ++ni) {
      int brow = wn*64 + ni*16 + (lane & 15);
      int off = brow*32 + ((g ^ (brow & 3)) << 3);
      bh[ni] = *(const f16x8*)&lds[buf][2][off];
      bl[ni] = *(const f16x8*)&lds[buf][3][off];
    }
    #pragma unroll
    for (int mi = 0; mi < 4; ++mi)
      #pragma unroll
      for (int ni = 0; ni < 4; ++ni) {
        acc[mi][ni] = __builtin_amdgcn_mfma_f32_16x16x32_f16(ah[mi], bh[ni], acc[mi][ni], 0, 0, 0);
        acc[mi][ni] = __builtin_amdgcn_mfma_f32_16x16x32_f16(ah[mi], bl[ni], acc[mi][ni], 0, 0, 0);
        acc[mi][ni] = __builtin_amdgcn_mfma_f32_16x16x32_f16(al[mi], bh[ni], acc[mi][ni], 0, 0, 0);
      }
  };

  stage(0, 0);
  asm volatile("s_waitcnt vmcnt(0)" ::: "memory");
  __syncthreads();
  int cur = 0;
  for (int kt = 0; kt < 24; ++kt) {
    if (kt < 23) stage(cur ^ 1, kt + 1);
    compute(cur);
    asm volatile("s_waitcnt vmcnt(0)" ::: "memory");
    __syncthreads();
    cur ^= 1;
  }

  // epilogue
  float* biasl = nullptr;
  if constexpr (MODE == 1) {
    biasl = (float*)&lds[0][0][0];
    if (tid < 128) biasl[tid] = bias[col0 + tid];
    __syncthreads();
  }
  #pragma unroll
  for (int mi = 0; mi < 4; ++mi) {
    #pragma unroll
    for (int t = 0; t < 4; ++t) {
      int r = row0 + wm*64 + mi*16 + (lane >> 4)*4 + t;
      if (r >= BNROWS) continue;
      if constexpr (MODE == 0) {
        int b_ = r / 197, n_ = r - b_*197;
        #pragma unroll
        for (int ni = 0; ni < 4; ++ni) {
          int o = col0 + wn*64 + ni*16 + (lane & 15);
          float val = acc[mi][ni][t];
          int tq = o / 768, rem = o - tq*768;
          int hh = rem >> 6, dd = rem & 63;
          size_t dst = ((size_t)(b_*12 + hh)*197 + n_)*64 + dd;
          if (tq == 0)      qb_[dst] = val;
          else if (tq == 1) kb_[dst] = val;
          else              vb_[dst] = f2h(val);
        }
      } else {
        #pragma unroll
        for (int ni = 0; ni < 4; ++ni) {
          int o = col0 + wn*64 + ni*16 + (lane & 15);
          dout[(size_t)r*768 + o] = acc[mi][ni][t] + biasl[o - col0];
        }
      }
    }
  }
}

// ---------------- Quantize q/k tokens 1..196, write f16 cat buffers + MSE partials ----------
__global__ __launch_bounds__(256)
void quant_kernel(const float* __restrict__ x, const float* __restrict__ qkv_w,
                  const float* __restrict__ qbuf, const float* __restrict__ kbuf,
                  const float* __restrict__ qe, const float* __restrict__ ke,
                  u16* __restrict__ cq, u16* __restrict__ ck, float* __restrict__ pq)
{
  __shared__ __align__(16) float Qt[64*197];   // transposed [i][tok], pad 197
  __shared__ __align__(16) float El[KCB*66];   // codebook, pad 66
  __shared__ double e2d[KCB];
  __shared__ int idxb[NM];
  __shared__ float wred[4];
  const int tid = threadIdx.x;
  const int bh = blockIdx.x;
  const int which = blockIdx.y;
  const int b_ = bh / 12, h_ = bh - b_*12;
  const float* feat = which ? kbuf : qbuf;
  const float* emb  = which ? ke : qe;
  u16* dst = which ? ck : cq;
  const size_t base = (size_t)bh * (197*64);

  for (int idx = tid; idx < KCB*64; idx += 256) {
    int kk = idx >> 6, i = idx & 63;
    El[kk*66 + i] = emb[h_*(KCB*64) + idx];
  }
  for (int idx = tid; idx < NM*64; idx += 256) {
    int mm = idx >> 6, i = idx & 63;
    Qt[i*197 + mm] = feat[base + (size_t)(mm+1)*64 + i];
  }
  // cls passthrough (token 0)
  if (tid >= 64 && tid < 128) {
    int i = tid - 64;
    dst[base + i] = f2h(feat[base + i]);
  }
  __syncthreads();
  if (tid < KCB) {
    double s = 0.0;
    for (int i = 0; i < 64; ++i) { double e = (double)El[tid*66 + i]; s += e*e; }
    e2d[tid] = s;
  }
  __syncthreads();

  const int tok = tid;
  double d1 = 1e300, d2 = 1e300;
  int bidx = 0;
  if (tok < NM) {
    for (int kc = 0; kc < 5; ++kc) {
      double dot[10];
      #pragma unroll
      for (int u = 0; u < 10; ++u) dot[u] = 0.0;
      for (int j = 0; j < 32; ++j) {
        double fx = (double)Qt[(2*j)*197 + tok];
        double fy = (double)Qt[(2*j+1)*197 + tok];
        #pragma unroll
        for (int u = 0; u < 10; ++u) {
          float2 ev = *(const float2*)&El[(kc*10+u)*66 + 2*j];
          dot[u] = fma(fx, (double)ev.x, dot[u]);
          dot[u] = fma(fy, (double)ev.y, dot[u]);
        }
      }
      #pragma unroll
      for (int u = 0; u < 10; ++u) {
        int kk = kc*10 + u;
        double dist = e2d[kk] - 2.0*dot[u];
        if (dist < d1) { d2 = d1; d1 = dist; bidx = kk; }
        else if (dist < d2) d2 = dist;
      }
    }
  }
  // exact fp64 rescue for near-ties (wave-cooperative)
  const int lane = tid & 63;
  u64 flags = __ballot(tok < NM && (d2 - d1) < 1e-3);
  while (flags) {
    int src = __ffsll(flags) - 1;
    flags &= flags - 1;
    int ftok = (tid & ~63) + src;
    int mrow = 1 + ftok;
    const float* xrow = x + (size_t)(b_*197 + mrow)*768;
    const float* wrow = qkv_w + (size_t)(which*768 + h_*64 + lane)*768;
    double qd = 0.0;
    for (int c = 0; c < 768; ++c) qd = fma((double)xrow[c], (double)wrow[c], qd);
    double bb = 1e300; int bi = 0;
    for (int kk = 0; kk < KCB; ++kk) {
      double df = qd - (double)El[kk*66 + lane];
      double sq = df*df;
      #pragma unroll
      for (int off = 32; off > 0; off >>= 1) sq += __shfl_xor(sq, off);
      if (sq < bb) { bb = sq; bi = kk; }
    }
    if (lane == src) bidx = bi;
  }
  if (tok < NM) idxb[tok] = bidx;
  __syncthreads();

  float msel = 0.f;
  for (int idx = tid; idx < NM*64; idx += 256) {
    int mm = idx >> 6, i = idx & 63;
    float ev = El[idxb[mm]*66 + i];
    float qv = Qt[i*197 + mm];
    float df = ev - qv;
    msel = fmaf(df, df, msel);
    dst[base + (size_t)(mm+1)*64 + i] = f2h(ev);
  }
  #pragma unroll
  for (int off = 32; off > 0; off >>= 1) msel += __shfl_down(msel, off);
  if (lane == 0) wred[tid >> 6] = msel;
  __syncthreads();
  if (tid == 0) pq[which*768 + bh] = wred[0]+wred[1]+wred[2]+wred[3];
}

// ---------------- fused: attn KL stats + quant_attn softmax + PV, no inner barriers --------
__global__ __launch_bounds__(256)
void fused_attn_kernel(const float* __restrict__ qbuf, const float* __restrict__ kbuf,
                       const u16* __restrict__ cq, const u16* __restrict__ ck,
                       const u16* __restrict__ vb,
                       u16* __restrict__ aoh, u16* __restrict__ aol,
                       float* __restrict__ pkl)
{
  __shared__ __align__(16) u32 Kl[197*32];
  __shared__ __align__(16) u32 CKl[197*32];
  __shared__ __align__(16) u32 Vl[197*32];
  __shared__ float red[257];
  const int tid = threadIdx.x;
  const int bh = blockIdx.x;
  const int b_ = bh / 12, h_ = bh - b_*12;
  const size_t base = (size_t)bh * (197*64);
  const u32* ck32 = (const u32*)ck;
  const u32* vb32 = (const u32*)vb;
  const size_t base2 = base >> 1;

  for (int idx = tid; idx < 197*32; idx += 256) {
    float2 kv = *(const float2*)(kbuf + base + 2*idx);
    Kl[idx] = packh2(kv.x, kv.y);
    CKl[idx] = ck32[base2 + idx];
    Vl[idx] = vb32[base2 + idx];
  }

  const int n = tid;
  u32 qr[32], cqr[32];
  if (n < 197) {
    #pragma unroll
    for (int j = 0; j < 16; ++j) {
      float4 qv = *(const float4*)(qbuf + base + (size_t)n*64 + j*4);
      qr[2*j]   = packh2(qv.x, qv.y);
      qr[2*j+1] = packh2(qv.z, qv.w);
    }
    const uint4* cp = (const uint4*)(cq + base + (size_t)n*64);
    #pragma unroll
    for (int j = 0; j < 8; ++j) {
      uint4 cu = cp[j];
      cqr[4*j] = cu.x; cqr[4*j+1] = cu.y; cqr[4*j+2] = cu.z; cqr[4*j+3] = cu.w;
    }
  }
  __syncthreads();

  float aM = -INFINITY, aS = 0.f, aT = 0.f;
  float qM = -INFINITY, qS = 0.f;
  float out[64];
  #pragma unroll
  for (int d = 0; d < 64; ++d) out[d] = 0.f;
  float cross = 0.f;

  if (n < 197) {
    for (int m = 0; m < 197; ++m) {
      const u32* kp  = &Kl[m*32];
      const u32* ckp = &CKl[m*32];
      float ad0 = 0.f, ad1 = 0.f, qd0 = 0.f, qd1 = 0.f;
      #pragma unroll
      for (int j = 0; j < 32; j += 2) {
        ad0 = dot2(as_h2(qr[j]),    as_h2(kp[j]),    ad0);
        ad1 = dot2(as_h2(qr[j+1]),  as_h2(kp[j+1]),  ad1);
        qd0 = dot2(as_h2(cqr[j]),   as_h2(ckp[j]),   qd0);
        qd1 = dot2(as_h2(cqr[j+1]), as_h2(ckp[j+1]), qd1);
      }
      float l  = (ad0 + ad1) * 0.125f;
      float ql = (qd0 + qd1) * 0.125f;
      float nM = fmaxf(aM, l);
      float sc = __expf(aM - nM);
      float e  = __expf(l - nM);
      aS = fmaf(aS, sc, e);
      aT = fmaf(aT, sc, e * l);
      aM = nM;
      float nQ = fmaxf(qM, ql);
      float qsc = __expf(qM - nQ);
      float qe  = __expf(ql - nQ);
      qS = fmaf(qS, qsc, qe);
      qM = nQ;
    }
    float aSi = __frcp_rn(aS);
    float qSi = __frcp_rn(qS);
    for (int m = 0; m < 197; ++m) {
      const u32* kp  = &Kl[m*32];
      const u32* ckp = &CKl[m*32];
      float ad0 = 0.f, ad1 = 0.f, qd0 = 0.f, qd1 = 0.f;
      #pragma unroll
      for (int j = 0; j < 32; j += 2) {
        ad0 = dot2(as_h2(qr[j]),    as_h2(kp[j]),    ad0);
        ad1 = dot2(as_h2(qr[j+1]),  as_h2(kp[j+1]),  ad1);
        qd0 = dot2(as_h2(cqr[j]),   as_h2(ckp[j]),   qd0);
        qd1 = dot2(as_h2(cqr[j+1]), as_h2(ckp[j+1]), qd1);
      }
      float l  = (ad0 + ad1) * 0.125f;
      float ql = (qd0 + qd1) * 0.125f;
      float a  = __expf(l - aM) * aSi;
      float qa = __expf(ql - qM) * qSi;
      cross = fmaf(a, qa, cross);
      const u32* vp = &Vl[m*32];
      #pragma unroll
      for (int j = 0; j < 32; ++j) {
        h2 v = as_h2(vp[j]);
        out[2*j]   = fmaf((float)v.x, qa, out[2*j]);
        out[2*j+1] = fmaf((float)v.y, qa, out[2*j+1]);
      }
    }
    // write PV row as f16 hi/lo planes (feeds the MFMA proj GEMM)
    size_t obase = ((size_t)(b_*197 + n))*768 + h_*64;
    #pragma unroll
    for (int j = 0; j < 16; ++j) {
      float a0 = out[4*j], a1 = out[4*j+1], a2 = out[4*j+2], a3 = out[4*j+3];
      *(uint2*)&aoh[obase + 4*j] = make_uint2(packh2(a0, a1), packh2(a2, a3));
      *(uint2*)&aol[obase + 4*j] = make_uint2(packh2(hres(a0), hres(a1)),
                                              packh2(hres(a2), hres(a3)));
    }
  }

  float kln = 0.f;
  if (n < 197) kln = aT * __frcp_rn(aS) - aM - __logf(aS) - cross;
  float tot = brSum(kln, red, tid);
  if (tid == 0) pkl[bh] = tot;
}

// ---------------- deterministic loss finalize ----------------
__global__ __launch_bounds__(256)
void finalize_kernel(const float* __restrict__ pq, const float* __restrict__ pkl,
                     float* __restrict__ dout)
{
  __shared__ double red[256];
  const int tid = threadIdx.x;
  double s0 = 0.0, s1 = 0.0;
  for (int i = tid; i < 1536; i += 256) s0 += (double)pq[i];
  for (int i = tid; i < 768; i += 256) s1 += (double)pkl[i];
  red[tid] = s0; __syncthreads();
  for (int off = 128; off > 0; off >>= 1) { if (tid < off) red[tid] += red[tid+off]; __syncthreads(); }
  double mse = red[0];
  __syncthreads();
  red[tid] = s1; __syncthreads();
  for (int off = 128; off > 0; off >>= 1) { if (tid < off) red[tid] += red[tid+off]; __syncthreads(); }
  double kl = red[0];
  if (tid == 0) dout[SZ] = (float)(mse / 9633792.0 + kl / 29805312.0);
}

extern "C" void kernel_launch(void* const* d_in, const int* in_sizes, int n_in,
                              void* d_out, int out_size, void* d_ws, size_t ws_size,
                              hipStream_t stream)
{
  const float* x      = (const float*)d_in[0];
  const float* qkv_w  = (const float*)d_in[1];
  const float* proj_w = (const float*)d_in[2];
  const float* proj_b = (const float*)d_in[3];
  const float* qe     = (const float*)d_in[4];
  const float* ke     = (const float*)d_in[5];
  float* out = (float*)d_out;

  float* ws  = (float*)d_ws;
  float* qb_ = ws;                       // SZ fp32
  float* kb_ = ws + SZ;                  // SZ fp32
  u16*   vb_ = (u16*)(ws + 2*SZ);        // SZ f16
  u16*   cq_ = vb_ + SZ;                 // SZ f16
  u16*   ck_ = cq_ + SZ;                 // SZ f16
  u16*   xh_ = ck_ + SZ;                 // SZ f16
  u16*   xl_ = xh_ + SZ;                 // SZ f16
  u16*   aoh_= xl_ + SZ;                 // SZ f16
  u16*   aol_= aoh_ + SZ;                // SZ f16
  u16*   wh_ = aol_ + SZ;                // WQKV f16
  u16*   wl_ = wh_ + WQKV;
  u16*   ph_ = wl_ + WQKV;               // WPRJ f16
  u16*   pl_ = ph_ + WPRJ;
  float* pq_ = (float*)(pl_ + WPRJ);     // 1536
  float* pkl_= pq_ + 1536;               // 768

  dim3 blk(256);
  split_kernel<<<dim3((int)(SZ/4/256)),   blk, 0, stream>>>(x, xh_, xl_, (int)(SZ/4));
  split_kernel<<<dim3((int)(WQKV/4/256)), blk, 0, stream>>>(qkv_w, wh_, wl_, (int)(WQKV/4));
  split_kernel<<<dim3((int)(WPRJ/4/256)), blk, 0, stream>>>(proj_w, ph_, pl_, (int)(WPRJ/4));
  gemm_mfma<0><<<dim3(99, 18), blk, 0, stream>>>(xh_, xl_, wh_, wl_, qb_, kb_, vb_, nullptr, nullptr);
  quant_kernel<<<dim3(768, 2), blk, 0, stream>>>(x, qkv_w, qb_, kb_, qe, ke, cq_, ck_, pq_);
  fused_attn_kernel<<<dim3(768), blk, 0, stream>>>(qb_, kb_, cq_, ck_, vb_, aoh_, aol_, pkl_);
  gemm_mfma<1><<<dim3(99, 6), blk, 0, stream>>>(aoh_, aol_, ph_, pl_, nullptr, nullptr, nullptr, proj_b, out);
  finalize_kernel<<<dim3(1), blk, 0, stream>>>(pq_, pkl_, out);
}

// Round 4
// 549.758 us; speedup vs baseline: 3.9849x; 1.4247x over previous
//
#include <hip/hip_runtime.h>
#include <math.h>

#define NB 64
#define NN 197
#define NC 768
#define NH 12
#define ND 64
#define KCB 50
#define NM (NN-1)                    // 196
#define BNROWS (NB*NN)               // 12608
#define SZ ((size_t)NB*NH*NN*ND)     // 9,682,944
#define WQKV ((size_t)2304*768)      // 1,769,472
#define WPRJ ((size_t)768*768)       // 589,824

typedef unsigned short u16;
typedef unsigned int u32;
typedef unsigned long long u64;
typedef _Float16 h2 __attribute__((ext_vector_type(2)));
typedef _Float16 f16x4 __attribute__((ext_vector_type(4)));
typedef _Float16 f16x8 __attribute__((ext_vector_type(8)));
typedef float f32x4 __attribute__((ext_vector_type(4)));

#define GLOAD16(gp, lp) __builtin_amdgcn_global_load_lds( \
    (const __attribute__((address_space(1))) void*)(gp),  \
    (__attribute__((address_space(3))) void*)(lp), 16, 0, 0)

__device__ __forceinline__ u16 f2h(float x) {
  _Float16 h = (_Float16)x;
  return *(u16*)&h;
}
__device__ __forceinline__ u32 packh2(float a, float b) {
  h2 v = { (_Float16)a, (_Float16)b };
  return *(u32*)&v;
}
__device__ __forceinline__ float hres(float x) {  // residue after f16 rounding
  _Float16 h = (_Float16)x;
  return x - (float)h;
}

// ---------------- split fp32 -> f16 hi/lo planes ----------------
__global__ __launch_bounds__(256)
void split_kernel(const float* __restrict__ src, u16* __restrict__ hi,
                  u16* __restrict__ lo, int n4)
{
  int i = blockIdx.x*256 + threadIdx.x;
  if (i >= n4) return;
  float4 v = ((const float4*)src)[i];
  _Float16 h0 = (_Float16)v.x, h1 = (_Float16)v.y, h2_ = (_Float16)v.z, h3 = (_Float16)v.w;
  uint2 hv = make_uint2((u32)*(u16*)&h0 | ((u32)*(u16*)&h1 << 16),
                        (u32)*(u16*)&h2_ | ((u32)*(u16*)&h3 << 16));
  ((uint2*)hi)[i] = hv;
  _Float16 l0 = (_Float16)(v.x - (float)h0), l1 = (_Float16)(v.y - (float)h1);
  _Float16 l2 = (_Float16)(v.z - (float)h2_), l3 = (_Float16)(v.w - (float)h3);
  uint2 lv = make_uint2((u32)*(u16*)&l0 | ((u32)*(u16*)&l1 << 16),
                        (u32)*(u16*)&l2 | ((u32)*(u16*)&l3 << 16));
  ((uint2*)lo)[i] = lv;
}

// ---------------- MFMA GEMM, f16 split-3, C[r,o] = sum_c A[r,c]*W[o,c] ----------------
template<int MODE>
__global__ __launch_bounds__(256)
void gemm_mfma(const u16* __restrict__ Ah, const u16* __restrict__ Al,
               const u16* __restrict__ Wh, const u16* __restrict__ Wl,
               float* __restrict__ qb_, float* __restrict__ kb_, u16* __restrict__ vb_,
               const float* __restrict__ bias, float* __restrict__ dout)
{
  __shared__ u16 lds[2][4][4096];   // [buf][Ah,Al,Bh,Bl][128 rows x 32 f16], 64 KB
  const int tid = threadIdx.x;
  const int lane = tid & 63, w = tid >> 6;
  const int wm = w >> 1, wn = w & 1;
  const int row0 = blockIdx.x * 128, col0 = blockIdx.y * 128;

  f32x4 acc[4][4];
  #pragma unroll
  for (int mi = 0; mi < 4; ++mi)
    #pragma unroll
    for (int ni = 0; ni < 4; ++ni) acc[mi][ni] = (f32x4){0.f, 0.f, 0.f, 0.f};

  auto stage = [&](int buf, int kt) {
    const int c0 = kt * 32;
    #pragma unroll
    for (int j = 0; j < 2; ++j) {
      const int r0 = w*32 + j*16;
      const int lrow = r0 + (lane >> 2);
      const int slot = (lane & 3) ^ (lrow & 3);
      int ar = row0 + lrow; if (ar > BNROWS-1) ar = BNROWS-1;
      const size_t ga = (size_t)ar * 768 + c0 + slot*8;
      const size_t gb = (size_t)(col0 + lrow) * 768 + c0 + slot*8;
      GLOAD16(Ah + ga, &lds[buf][0][r0*32]);
      GLOAD16(Al + ga, &lds[buf][1][r0*32]);
      GLOAD16(Wh + gb, &lds[buf][2][r0*32]);
      GLOAD16(Wl + gb, &lds[buf][3][r0*32]);
    }
  };

  auto compute = [&](int buf) {
    f16x8 ah[4], al[4], bh[4], bl[4];
    const int g = lane >> 4;
    #pragma unroll
    for (int mi = 0; mi < 4; ++mi) {
      int arow = wm*64 + mi*16 + (lane & 15);
      int off = arow*32 + ((g ^ (arow & 3)) << 3);
      ah[mi] = *(const f16x8*)&lds[buf][0][off];
      al[mi] = *(const f16x8*)&lds[buf][1][off];
    }
    #pragma unroll
    for (int ni = 0; ni < 4; ++ni) {
      int brow = wn*64 + ni*16 + (lane & 15);
      int off = brow*32 + ((g ^ (brow & 3)) << 3);
      bh[ni] = *(const f16x8*)&lds[buf][2][off];
      bl[ni] = *(const f16x8*)&lds[buf][3][off];
    }
    #pragma unroll
    for (int mi = 0; mi < 4; ++mi)
      #pragma unroll
      for (int ni = 0; ni < 4; ++ni) {
        acc[mi][ni] = __builtin_amdgcn_mfma_f32_16x16x32_f16(ah[mi], bh[ni], acc[mi][ni], 0, 0, 0);
        acc[mi][ni] = __builtin_amdgcn_mfma_f32_16x16x32_f16(ah[mi], bl[ni], acc[mi][ni], 0, 0, 0);
        acc[mi][ni] = __builtin_amdgcn_mfma_f32_16x16x32_f16(al[mi], bh[ni], acc[mi][ni], 0, 0, 0);
      }
  };

  stage(0, 0);
  asm volatile("s_waitcnt vmcnt(0)" ::: "memory");
  __syncthreads();
  int cur = 0;
  for (int kt = 0; kt < 24; ++kt) {
    if (kt < 23) stage(cur ^ 1, kt + 1);
    compute(cur);
    asm volatile("s_waitcnt vmcnt(0)" ::: "memory");
    __syncthreads();
    cur ^= 1;
  }

  float* biasl = nullptr;
  if constexpr (MODE == 1) {
    biasl = (float*)&lds[0][0][0];
    if (tid < 128) biasl[tid] = bias[col0 + tid];
    __syncthreads();
  }
  #pragma unroll
  for (int mi = 0; mi < 4; ++mi) {
    #pragma unroll
    for (int t = 0; t < 4; ++t) {
      int r = row0 + wm*64 + mi*16 + (lane >> 4)*4 + t;
      if (r >= BNROWS) continue;
      if constexpr (MODE == 0) {
        int b_ = r / 197, n_ = r - b_*197;
        #pragma unroll
        for (int ni = 0; ni < 4; ++ni) {
          int o = col0 + wn*64 + ni*16 + (lane & 15);
          float val = acc[mi][ni][t];
          int tq = o / 768, rem = o - tq*768;
          int hh = rem >> 6, dd = rem & 63;
          size_t dst = ((size_t)(b_*12 + hh)*197 + n_)*64 + dd;
          if (tq == 0)      qb_[dst] = val;
          else if (tq == 1) kb_[dst] = val;
          else              vb_[dst] = f2h(val);
        }
      } else {
        #pragma unroll
        for (int ni = 0; ni < 4; ++ni) {
          int o = col0 + wn*64 + ni*16 + (lane & 15);
          dout[(size_t)r*768 + o] = acc[mi][ni][t] + biasl[o - col0];
        }
      }
    }
  }
}

// ---------------- Quantize q/k tokens 1..196, write f16 cat buffers + MSE partials ----------
__global__ __launch_bounds__(256)
void quant_kernel(const float* __restrict__ x, const float* __restrict__ qkv_w,
                  const float* __restrict__ qbuf, const float* __restrict__ kbuf,
                  const float* __restrict__ qe, const float* __restrict__ ke,
                  u16* __restrict__ cq, u16* __restrict__ ck, float* __restrict__ pq)
{
  __shared__ __align__(16) float Qt[64*197];
  __shared__ __align__(16) float El[KCB*66];
  __shared__ double e2d[KCB];
  __shared__ int idxb[NM];
  __shared__ float wred[4];
  const int tid = threadIdx.x;
  const int bh = blockIdx.x;
  const int which = blockIdx.y;
  const int b_ = bh / 12, h_ = bh - b_*12;
  const float* feat = which ? kbuf : qbuf;
  const float* emb  = which ? ke : qe;
  u16* dst = which ? ck : cq;
  const size_t base = (size_t)bh * (197*64);

  for (int idx = tid; idx < KCB*64; idx += 256) {
    int kk = idx >> 6, i = idx & 63;
    El[kk*66 + i] = emb[h_*(KCB*64) + idx];
  }
  for (int idx = tid; idx < NM*64; idx += 256) {
    int mm = idx >> 6, i = idx & 63;
    Qt[i*197 + mm] = feat[base + (size_t)(mm+1)*64 + i];
  }
  if (tid >= 64 && tid < 128) {
    int i = tid - 64;
    dst[base + i] = f2h(feat[base + i]);
  }
  __syncthreads();
  if (tid < KCB) {
    double s = 0.0;
    for (int i = 0; i < 64; ++i) { double e = (double)El[tid*66 + i]; s += e*e; }
    e2d[tid] = s;
  }
  __syncthreads();

  const int tok = tid;
  double d1 = 1e300, d2 = 1e300;
  int bidx = 0;
  if (tok < NM) {
    for (int kc = 0; kc < 5; ++kc) {
      double dot[10];
      #pragma unroll
      for (int u = 0; u < 10; ++u) dot[u] = 0.0;
      for (int j = 0; j < 32; ++j) {
        double fx = (double)Qt[(2*j)*197 + tok];
        double fy = (double)Qt[(2*j+1)*197 + tok];
        #pragma unroll
        for (int u = 0; u < 10; ++u) {
          float2 ev = *(const float2*)&El[(kc*10+u)*66 + 2*j];
          dot[u] = fma(fx, (double)ev.x, dot[u]);
          dot[u] = fma(fy, (double)ev.y, dot[u]);
        }
      }
      #pragma unroll
      for (int u = 0; u < 10; ++u) {
        int kk = kc*10 + u;
        double dist = e2d[kk] - 2.0*dot[u];
        if (dist < d1) { d2 = d1; d1 = dist; bidx = kk; }
        else if (dist < d2) d2 = dist;
      }
    }
  }
  const int lane = tid & 63;
  u64 flags = __ballot(tok < NM && (d2 - d1) < 1e-3);
  while (flags) {
    int src = __ffsll(flags) - 1;
    flags &= flags - 1;
    int ftok = (tid & ~63) + src;
    int mrow = 1 + ftok;
    const float* xrow = x + (size_t)(b_*197 + mrow)*768;
    const float* wrow = qkv_w + (size_t)(which*768 + h_*64 + lane)*768;
    double qd = 0.0;
    for (int c = 0; c < 768; ++c) qd = fma((double)xrow[c], (double)wrow[c], qd);
    double bb = 1e300; int bi = 0;
    for (int kk = 0; kk < KCB; ++kk) {
      double df = qd - (double)El[kk*66 + lane];
      double sq = df*df;
      #pragma unroll
      for (int off = 32; off > 0; off >>= 1) sq += __shfl_xor(sq, off);
      if (sq < bb) { bb = sq; bi = kk; }
    }
    if (lane == src) bidx = bi;
  }
  if (tok < NM) idxb[tok] = bidx;
  __syncthreads();

  float msel = 0.f;
  for (int idx = tid; idx < NM*64; idx += 256) {
    int mm = idx >> 6, i = idx & 63;
    float ev = El[idxb[mm]*66 + i];
    float qv = Qt[i*197 + mm];
    float df = ev - qv;
    msel = fmaf(df, df, msel);
    dst[base + (size_t)(mm+1)*64 + i] = f2h(ev);
  }
  #pragma unroll
  for (int off = 32; off > 0; off >>= 1) msel += __shfl_down(msel, off);
  if (lane == 0) wred[tid >> 6] = msel;
  __syncthreads();
  if (tid == 0) pq[which*768 + bh] = wred[0]+wred[1]+wred[2]+wred[3];
}

// ---------------- fused attention via MFMA: S^T = K*Q^T, online 2-pass, PV fused ----------
// D-layout of S^T: col(lane&15)=n, rows=m -> per-n stats via 2 shfl_xor.
// qa in exactly mfma_16x16x16 A-frag layout -> PV with no data movement.
__global__ __launch_bounds__(256)
void fused_attn_mfma(const float* __restrict__ qbuf, const float* __restrict__ kbuf,
                     const u16* __restrict__ cq, const u16* __restrict__ ck,
                     const u16* __restrict__ vb,
                     u16* __restrict__ aoh, u16* __restrict__ aol,
                     float* __restrict__ pkl)
{
  __shared__ __align__(16) u16 Kf[200*64];    // XOR-swizzled rows (slot^=row&7)
  __shared__ __align__(16) u16 CKf[200*64];
  __shared__ __align__(16) u16 Vt[64*212];    // V transposed [d][m], stride 212
  __shared__ float wred[4];
  const int tid = threadIdx.x;
  const int bh = blockIdx.x;
  const int b_ = bh / 12, h_ = bh - b_*12;
  const size_t base = (size_t)bh * (197*64);
  const u32* ck32 = (const u32*)ck;
  const u32* vb32 = (const u32*)vb;
  const size_t base2 = base >> 1;

  // stage: K (fp32->f16, swizzled), CK (swizzled), V transposed
  for (int idx = tid; idx < 197*32; idx += 256) {
    int m = idx >> 5, j = idx & 31;
    int dsti = m*32 + (((j >> 2) ^ (m & 7)) << 2) + (j & 3);
    float2 kv = *(const float2*)(kbuf + base + 2*idx);
    ((u32*)Kf)[dsti] = packh2(kv.x, kv.y);
    ((u32*)CKf)[dsti] = ck32[base2 + idx];
    u32 v2 = vb32[base2 + idx];
    Vt[(2*j)*212 + m]   = (u16)(v2 & 0xffff);
    Vt[(2*j+1)*212 + m] = (u16)(v2 >> 16);
  }
  // zero K/CK rows 197..199 and Vt cols 197..211
  for (int idx = tid; idx < 96; idx += 256) {
    int m = 197 + (idx >> 5), j = idx & 31;
    int dsti = m*32 + (((j >> 2) ^ (m & 7)) << 2) + (j & 3);
    ((u32*)Kf)[dsti] = 0; ((u32*)CKf)[dsti] = 0;
  }
  for (int idx = tid; idx < 64*15; idx += 256) {
    int d = idx / 15, mc = 197 + idx % 15;
    Vt[d*212 + mc] = 0;
  }
  __syncthreads();

  const int lane = tid & 63, w = tid >> 6;
  const int ln = lane & 15, g = lane >> 4;
  float klacc = 0.f;

  for (int nt = w; nt < 13; nt += 4) {
    const int n0 = nt*16;
    const int nb = n0 + ln;
    // B-frags: Q (fp32->f16) and CQ rows, k-halves s=0,1
    const float* qrow = qbuf + base + (size_t)nb*64;
    f16x8 fq[2], fcq[2];
    #pragma unroll
    for (int s = 0; s < 2; ++s) {
      float4 q0 = *(const float4*)(qrow + s*32 + g*8);
      float4 q1 = *(const float4*)(qrow + s*32 + g*8 + 4);
      fq[s] = (f16x8){(_Float16)q0.x,(_Float16)q0.y,(_Float16)q0.z,(_Float16)q0.w,
                      (_Float16)q1.x,(_Float16)q1.y,(_Float16)q1.z,(_Float16)q1.w};
      uint4 cu = *(const uint4*)(cq + base + (size_t)nb*64 + s*32 + g*8);
      *(uint4*)&fcq[s] = cu;
    }

    // ---- pass 1: max of raw scores ----
    float Ma = -3e38f, Mq = -3e38f;
    for (int t = 0; t < 13; ++t) {
      int mrow = t*16 + ln; if (mrow > 199) mrow = 199;
      const char* kb8 = (const char*)Kf + mrow*128;
      const char* cb8 = (const char*)CKf + mrow*128;
      int sw = (mrow & 7) << 4;
      f32x4 sa = (f32x4){0.f,0.f,0.f,0.f}, sq = (f32x4){0.f,0.f,0.f,0.f};
      sa = __builtin_amdgcn_mfma_f32_16x16x32_f16(*(const f16x8*)(kb8 + (( g     <<4) ^ sw)), fq[0], sa, 0,0,0);
      sa = __builtin_amdgcn_mfma_f32_16x16x32_f16(*(const f16x8*)(kb8 + (((4+g)<<4) ^ sw)), fq[1], sa, 0,0,0);
      sq = __builtin_amdgcn_mfma_f32_16x16x32_f16(*(const f16x8*)(cb8 + (( g     <<4) ^ sw)), fcq[0], sq, 0,0,0);
      sq = __builtin_amdgcn_mfma_f32_16x16x32_f16(*(const f16x8*)(cb8 + (((4+g)<<4) ^ sw)), fcq[1], sq, 0,0,0);
      int mbase = t*16 + g*4;
      #pragma unroll
      for (int r = 0; r < 4; ++r) {
        bool v = (mbase + r) < 197;
        Ma = fmaxf(Ma, v ? sa[r] : -3e38f);
        Mq = fmaxf(Mq, v ? sq[r] : -3e38f);
      }
    }
    Ma = fmaxf(Ma, __shfl_xor(Ma, 16)); Ma = fmaxf(Ma, __shfl_xor(Ma, 32));
    Mq = fmaxf(Mq, __shfl_xor(Mq, 16)); Mq = fmaxf(Mq, __shfl_xor(Mq, 32));

    // ---- pass 2: accumulate sums, cross, PV (unnormalized) ----
    const float Mla = Ma * 0.125f, Mlq = Mq * 0.125f;
    float aS = 0.f, aT = 0.f, qS = 0.f, cross = 0.f;
    f32x4 ov[4];
    #pragma unroll
    for (int dt = 0; dt < 4; ++dt) ov[dt] = (f32x4){0.f,0.f,0.f,0.f};
    for (int t = 0; t < 13; ++t) {
      int mrow = t*16 + ln; if (mrow > 199) mrow = 199;
      const char* kb8 = (const char*)Kf + mrow*128;
      const char* cb8 = (const char*)CKf + mrow*128;
      int sw = (mrow & 7) << 4;
      f32x4 sa = (f32x4){0.f,0.f,0.f,0.f}, sq = (f32x4){0.f,0.f,0.f,0.f};
      sa = __builtin_amdgcn_mfma_f32_16x16x32_f16(*(const f16x8*)(kb8 + (( g     <<4) ^ sw)), fq[0], sa, 0,0,0);
      sa = __builtin_amdgcn_mfma_f32_16x16x32_f16(*(const f16x8*)(kb8 + (((4+g)<<4) ^ sw)), fq[1], sa, 0,0,0);
      sq = __builtin_amdgcn_mfma_f32_16x16x32_f16(*(const f16x8*)(cb8 + (( g     <<4) ^ sw)), fcq[0], sq, 0,0,0);
      sq = __builtin_amdgcn_mfma_f32_16x16x32_f16(*(const f16x8*)(cb8 + (((4+g)<<4) ^ sw)), fcq[1], sq, 0,0,0);
      int mbase = t*16 + g*4;
      float eqv[4];
      #pragma unroll
      for (int r = 0; r < 4; ++r) {
        bool v = (mbase + r) < 197;
        float ea = v ? __expf(fmaf(sa[r], 0.125f, -Mla)) : 0.f;
        float eq = v ? __expf(fmaf(sq[r], 0.125f, -Mlq)) : 0.f;
        aS += ea;
        aT = fmaf(ea, sa[r], aT);
        qS += eq;
        cross = fmaf(ea, eq, cross);
        eqv[r] = eq;
      }
      f16x4 qaf = {(_Float16)eqv[0], (_Float16)eqv[1], (_Float16)eqv[2], (_Float16)eqv[3]};
      #pragma unroll
      for (int dt = 0; dt < 4; ++dt) {
        f16x4 bv = *(const f16x4*)(Vt + (dt*16 + ln)*212 + t*16 + g*4);
        ov[dt] = __builtin_amdgcn_mfma_f32_16x16x16f16(qaf, bv, ov[dt], 0, 0, 0);
      }
    }
    aS += __shfl_xor(aS, 16); aS += __shfl_xor(aS, 32);
    aT += __shfl_xor(aT, 16); aT += __shfl_xor(aT, 32);
    qS += __shfl_xor(qS, 16); qS += __shfl_xor(qS, 32);
    cross += __shfl_xor(cross, 16); cross += __shfl_xor(cross, 32);

    if (g == 0 && nb < 197) {
      float rowkl = 0.125f*(aT/aS) - Mla - __logf(aS) - cross/(aS*qS);
      klacc += rowkl;
    }
    // output: D-layout col=lane&15=d_local, rows n = n0+g*4+r
    #pragma unroll
    for (int r = 0; r < 4; ++r) {
      int nl = g*4 + r;
      int nglob = n0 + nl;
      if (nglob >= 197) continue;
      float qSn = __shfl(qS, nl);
      float inv = __frcp_rn(qSn);
      size_t obase = ((size_t)(b_*197 + nglob))*768 + h_*64;
      #pragma unroll
      for (int dt = 0; dt < 4; ++dt) {
        float val = ov[dt][r] * inv;
        aoh[obase + dt*16 + ln] = f2h(val);
        aol[obase + dt*16 + ln] = f2h(hres(val));
      }
    }
  }

  // block KL reduce
  #pragma unroll
  for (int off = 32; off > 0; off >>= 1) klacc += __shfl_down(klacc, off);
  if (lane == 0) wred[w] = klacc;
  __syncthreads();
  if (tid == 0) pkl[bh] = wred[0] + wred[1] + wred[2] + wred[3];
}

// ---------------- deterministic loss finalize ----------------
__global__ __launch_bounds__(256)
void finalize_kernel(const float* __restrict__ pq, const float* __restrict__ pkl,
                     float* __restrict__ dout)
{
  __shared__ double red[256];
  const int tid = threadIdx.x;
  double s0 = 0.0, s1 = 0.0;
  for (int i = tid; i < 1536; i += 256) s0 += (double)pq[i];
  for (int i = tid; i < 768; i += 256) s1 += (double)pkl[i];
  red[tid] = s0; __syncthreads();
  for (int off = 128; off > 0; off >>= 1) { if (tid < off) red[tid] += red[tid+off]; __syncthreads(); }
  double mse = red[0];
  __syncthreads();
  red[tid] = s1; __syncthreads();
  for (int off = 128; off > 0; off >>= 1) { if (tid < off) red[tid] += red[tid+off]; __syncthreads(); }
  double kl = red[0];
  if (tid == 0) dout[SZ] = (float)(mse / 9633792.0 + kl / 29805312.0);
}

extern "C" void kernel_launch(void* const* d_in, const int* in_sizes, int n_in,
                              void* d_out, int out_size, void* d_ws, size_t ws_size,
                              hipStream_t stream)
{
  const float* x      = (const float*)d_in[0];
  const float* qkv_w  = (const float*)d_in[1];
  const float* proj_w = (const float*)d_in[2];
  const float* proj_b = (const float*)d_in[3];
  const float* qe     = (const float*)d_in[4];
  const float* ke     = (const float*)d_in[5];
  float* out = (float*)d_out;

  float* ws  = (float*)d_ws;
  float* qb_ = ws;                       // SZ fp32
  float* kb_ = ws + SZ;                  // SZ fp32
  u16*   vb_ = (u16*)(ws + 2*SZ);        // SZ f16
  u16*   cq_ = vb_ + SZ;                 // SZ f16
  u16*   ck_ = cq_ + SZ;                 // SZ f16
  u16*   xh_ = ck_ + SZ;                 // SZ f16
  u16*   xl_ = xh_ + SZ;                 // SZ f16
  u16*   aoh_= xl_ + SZ;                 // SZ f16
  u16*   aol_= aoh_ + SZ;                // SZ f16
  u16*   wh_ = aol_ + SZ;                // WQKV f16
  u16*   wl_ = wh_ + WQKV;
  u16*   ph_ = wl_ + WQKV;               // WPRJ f16
  u16*   pl_ = ph_ + WPRJ;
  float* pq_ = (float*)(pl_ + WPRJ);     // 1536
  float* pkl_= pq_ + 1536;               // 768

  dim3 blk(256);
  split_kernel<<<dim3((int)(SZ/4/256)),   blk, 0, stream>>>(x, xh_, xl_, (int)(SZ/4));
  split_kernel<<<dim3((int)(WQKV/4/256)), blk, 0, stream>>>(qkv_w, wh_, wl_, (int)(WQKV/4));
  split_kernel<<<dim3((int)(WPRJ/4/256)), blk, 0, stream>>>(proj_w, ph_, pl_, (int)(WPRJ/4));
  gemm_mfma<0><<<dim3(99, 18), blk, 0, stream>>>(xh_, xl_, wh_, wl_, qb_, kb_, vb_, nullptr, nullptr);
  quant_kernel<<<dim3(768, 2), blk, 0, stream>>>(x, qkv_w, qb_, kb_, qe, ke, cq_, ck_, pq_);
  fused_attn_mfma<<<dim3(768), blk, 0, stream>>>(qb_, kb_, cq_, ck_, vb_, aoh_, aol_, pkl_);
  gemm_mfma<1><<<dim3(99, 6), blk, 0, stream>>>(aoh_, aol_, ph_, pl_, nullptr, nullptr, nullptr, proj_b, out);
  finalize_kernel<<<dim3(1), blk, 0, stream>>>(pq_, pkl_, out);
}

// Round 5
// 465.577 us; speedup vs baseline: 4.7055x; 1.1808x over previous
//
#include <hip/hip_runtime.h>
#include <math.h>

#define NB 64
#define NN 197
#define NC 768
#define NH 12
#define ND 64
#define KCB 50
#define NM (NN-1)                    // 196
#define BNROWS (NB*NN)               // 12608
#define SZ ((size_t)NB*NH*NN*ND)     // 9,682,944
#define WQKV ((size_t)2304*768)      // 1,769,472
#define WPRJ ((size_t)768*768)       // 589,824

typedef unsigned short u16;
typedef unsigned int u32;
typedef unsigned long long u64;
typedef _Float16 h2 __attribute__((ext_vector_type(2)));
typedef _Float16 f16x4 __attribute__((ext_vector_type(4)));
typedef _Float16 f16x8 __attribute__((ext_vector_type(8)));
typedef float f32x4 __attribute__((ext_vector_type(4)));

#define GLOAD16(gp, lp) __builtin_amdgcn_global_load_lds( \
    (const __attribute__((address_space(1))) void*)(gp),  \
    (__attribute__((address_space(3))) void*)(lp), 16, 0, 0)

__device__ __forceinline__ u16 f2h(float x) {
  _Float16 h = (_Float16)x;
  return *(u16*)&h;
}
__device__ __forceinline__ u32 packh2(float a, float b) {
  h2 v = { (_Float16)a, (_Float16)b };
  return *(u32*)&v;
}
__device__ __forceinline__ float hres(float x) {  // residue after f16 rounding
  _Float16 h = (_Float16)x;
  return x - (float)h;
}

// ---------------- split fp32 -> f16 hi/lo planes ----------------
__global__ __launch_bounds__(256)
void split_kernel(const float* __restrict__ src, u16* __restrict__ hi,
                  u16* __restrict__ lo, int n4)
{
  int i = blockIdx.x*256 + threadIdx.x;
  if (i >= n4) return;
  float4 v = ((const float4*)src)[i];
  _Float16 h0 = (_Float16)v.x, h1 = (_Float16)v.y, h2_ = (_Float16)v.z, h3 = (_Float16)v.w;
  uint2 hv = make_uint2((u32)*(u16*)&h0 | ((u32)*(u16*)&h1 << 16),
                        (u32)*(u16*)&h2_ | ((u32)*(u16*)&h3 << 16));
  ((uint2*)hi)[i] = hv;
  _Float16 l0 = (_Float16)(v.x - (float)h0), l1 = (_Float16)(v.y - (float)h1);
  _Float16 l2 = (_Float16)(v.z - (float)h2_), l3 = (_Float16)(v.w - (float)h3);
  uint2 lv = make_uint2((u32)*(u16*)&l0 | ((u32)*(u16*)&l1 << 16),
                        (u32)*(u16*)&l2 | ((u32)*(u16*)&l3 << 16));
  ((uint2*)lo)[i] = lv;
}

// ---------------- MFMA GEMM, f16 split-3, C[r,o] = sum_c A[r,c]*W[o,c] ----------------
// swizzle: LDS row r slot s holds global slot s ^ (r&3) ^ ((r>>2)&3) -> rows sharing a
// bank-half spread across all 4 slots (2-way = free, m136).
template<int MODE>
__global__ __launch_bounds__(256)
void gemm_mfma(const u16* __restrict__ Ah, const u16* __restrict__ Al,
               const u16* __restrict__ Wh, const u16* __restrict__ Wl,
               float* __restrict__ qb_, float* __restrict__ kb_, u16* __restrict__ vb_,
               const float* __restrict__ bias, float* __restrict__ dout)
{
  __shared__ u16 lds[2][4][4096];   // [buf][Ah,Al,Bh,Bl][128 rows x 32 f16], 64 KB
  const int tid = threadIdx.x;
  const int lane = tid & 63, w = tid >> 6;
  const int wm = w >> 1, wn = w & 1;
  const int row0 = blockIdx.x * 128, col0 = blockIdx.y * 128;

  f32x4 acc[4][4];
  #pragma unroll
  for (int mi = 0; mi < 4; ++mi)
    #pragma unroll
    for (int ni = 0; ni < 4; ++ni) acc[mi][ni] = (f32x4){0.f, 0.f, 0.f, 0.f};

  auto stage = [&](int buf, int kt) {
    const int c0 = kt * 32;
    #pragma unroll
    for (int j = 0; j < 2; ++j) {
      const int r0 = w*32 + j*16;
      const int lrow = r0 + (lane >> 2);
      const int slot = (lane & 3) ^ (lrow & 3) ^ ((lrow >> 2) & 3);
      int ar = row0 + lrow; if (ar > BNROWS-1) ar = BNROWS-1;
      const size_t ga = (size_t)ar * 768 + c0 + slot*8;
      const size_t gb = (size_t)(col0 + lrow) * 768 + c0 + slot*8;
      GLOAD16(Ah + ga, &lds[buf][0][r0*32]);
      GLOAD16(Al + ga, &lds[buf][1][r0*32]);
      GLOAD16(Wh + gb, &lds[buf][2][r0*32]);
      GLOAD16(Wl + gb, &lds[buf][3][r0*32]);
    }
  };

  auto compute = [&](int buf) {
    f16x8 ah[4], al[4], bh[4], bl[4];
    const int g = lane >> 4;
    #pragma unroll
    for (int mi = 0; mi < 4; ++mi) {
      int arow = wm*64 + mi*16 + (lane & 15);
      int off = arow*32 + ((g ^ (arow & 3) ^ ((arow >> 2) & 3)) << 3);
      ah[mi] = *(const f16x8*)&lds[buf][0][off];
      al[mi] = *(const f16x8*)&lds[buf][1][off];
    }
    #pragma unroll
    for (int ni = 0; ni < 4; ++ni) {
      int brow = wn*64 + ni*16 + (lane & 15);
      int off = brow*32 + ((g ^ (brow & 3) ^ ((brow >> 2) & 3)) << 3);
      bh[ni] = *(const f16x8*)&lds[buf][2][off];
      bl[ni] = *(const f16x8*)&lds[buf][3][off];
    }
    #pragma unroll
    for (int mi = 0; mi < 4; ++mi)
      #pragma unroll
      for (int ni = 0; ni < 4; ++ni) {
        acc[mi][ni] = __builtin_amdgcn_mfma_f32_16x16x32_f16(ah[mi], bh[ni], acc[mi][ni], 0, 0, 0);
        acc[mi][ni] = __builtin_amdgcn_mfma_f32_16x16x32_f16(ah[mi], bl[ni], acc[mi][ni], 0, 0, 0);
        acc[mi][ni] = __builtin_amdgcn_mfma_f32_16x16x32_f16(al[mi], bh[ni], acc[mi][ni], 0, 0, 0);
      }
  };

  stage(0, 0);
  asm volatile("s_waitcnt vmcnt(0)" ::: "memory");
  __syncthreads();
  int cur = 0;
  for (int kt = 0; kt < 24; ++kt) {
    if (kt < 23) stage(cur ^ 1, kt + 1);
    compute(cur);
    asm volatile("s_waitcnt vmcnt(0)" ::: "memory");
    __syncthreads();
    cur ^= 1;
  }

  float* biasl = nullptr;
  if constexpr (MODE == 1) {
    biasl = (float*)&lds[0][0][0];
    if (tid < 128) biasl[tid] = bias[col0 + tid];
    __syncthreads();
  }
  #pragma unroll
  for (int mi = 0; mi < 4; ++mi) {
    #pragma unroll
    for (int t = 0; t < 4; ++t) {
      int r = row0 + wm*64 + mi*16 + (lane >> 4)*4 + t;
      if (r >= BNROWS) continue;
      if constexpr (MODE == 0) {
        int b_ = r / 197, n_ = r - b_*197;
        #pragma unroll
        for (int ni = 0; ni < 4; ++ni) {
          int o = col0 + wn*64 + ni*16 + (lane & 15);
          float val = acc[mi][ni][t];
          int tq = o / 768, rem = o - tq*768;
          int hh = rem >> 6, dd = rem & 63;
          size_t dst = ((size_t)(b_*12 + hh)*197 + n_)*64 + dd;
          if (tq == 0)      qb_[dst] = val;
          else if (tq == 1) kb_[dst] = val;
          else              vb_[dst] = f2h(val);
        }
      } else {
        #pragma unroll
        for (int ni = 0; ni < 4; ++ni) {
          int o = col0 + wn*64 + ni*16 + (lane & 15);
          dout[(size_t)r*768 + o] = acc[mi][ni][t] + biasl[o - col0];
        }
      }
    }
  }
}

// ---------------- Quantize via MFMA distance GEMM + fp64 rescue for near-ties ----------
// dist[c,tok] = e2[c] - 2*(E.F) via f16 split-3 MFMA (err ~3e-5 << 1e-3 rescue threshold).
// D-layout: col=lane&15=token, row=code=t*16+g*4+r (same mapping as fused_attn_mfma).
// MSE comes free: d1 + f2 (no elementwise pass).
__global__ __launch_bounds__(256)
void quant_mfma(const float* __restrict__ x, const float* __restrict__ qkv_w,
                const float* __restrict__ qbuf, const float* __restrict__ kbuf,
                const float* __restrict__ qe, const float* __restrict__ ke,
                u16* __restrict__ cq, u16* __restrict__ ck, float* __restrict__ pq)
{
  __shared__ __align__(16) float El[KCB*66];    // codebook fp32 (pad 66)
  __shared__ __align__(16) u16 Ehi[64*64];      // codebook f16 hi (rows 50..63 zero)
  __shared__ __align__(16) u16 Elo[64*64];      // codebook f16 lo
  __shared__ double e2d[KCB];
  __shared__ int idxb[NM];
  __shared__ float wred[4];
  const int tid = threadIdx.x;
  const int bh = blockIdx.x;
  const int which = blockIdx.y;
  const int b_ = bh / 12, h_ = bh - b_*12;
  const float* feat = which ? kbuf : qbuf;
  const float* emb  = which ? ke : qe;
  u16* dst = which ? ck : cq;
  const size_t base = (size_t)bh * (197*64);
  const int lane = tid & 63, w = tid >> 6;
  const int ln = lane & 15, g = lane >> 4;

  // stage codebook
  for (int idx = tid; idx < KCB*64; idx += 256) {
    int kk = idx >> 6, i = idx & 63;
    float v = emb[h_*(KCB*64) + idx];
    El[kk*66 + i] = v;
    _Float16 hv = (_Float16)v;
    Ehi[idx] = *(u16*)&hv;
    _Float16 lv = (_Float16)(v - (float)hv);
    Elo[idx] = *(u16*)&lv;
  }
  for (int idx = tid; idx < 14*64; idx += 256) {
    Ehi[KCB*64 + idx] = 0; Elo[KCB*64 + idx] = 0;
  }
  // cls passthrough (token 0)
  if (tid >= 64 && tid < 128) {
    int i = tid - 64;
    dst[base + i] = f2h(feat[base + i]);
  }
  __syncthreads();
  if (tid < KCB) {
    double s = 0.0;
    for (int i = 0; i < 64; ++i) { double e = (double)El[tid*66 + i]; s += e*e; }
    e2d[tid] = s;
  }
  __syncthreads();

  // hoist codebook A-frags + e2 into registers
  f16x8 Eah[4][2], Eal[4][2];
  float e2l[4][4];
  #pragma unroll
  for (int t = 0; t < 4; ++t) {
    #pragma unroll
    for (int s = 0; s < 2; ++s) {
      int off = (t*16 + ln)*64 + s*32 + g*8;
      Eah[t][s] = *(const f16x8*)&Ehi[off];
      Eal[t][s] = *(const f16x8*)&Elo[off];
    }
    #pragma unroll
    for (int r = 0; r < 4; ++r) {
      int c = t*16 + g*4 + r;
      e2l[t][r] = (c < KCB) ? (float)e2d[c] : 1e30f;
    }
  }

  float msum = 0.f;
  for (int nt = w; nt < 13; nt += 4) {
    int tok = nt*16 + ln;                   // tile token index (global row tok+1)
    int tokc = tok < NM ? tok : NM-1;
    const float* frow = feat + base + (size_t)(tokc+1)*64;
    // B-frags (token rows) fp32 -> f16 hi/lo; f2 partial on the fly
    f16x8 fqh[2], fql[2];
    float f2 = 0.f;
    #pragma unroll
    for (int s = 0; s < 2; ++s) {
      float4 q0 = *(const float4*)(frow + s*32 + g*8);
      float4 q1 = *(const float4*)(frow + s*32 + g*8 + 4);
      float vv[8] = {q0.x,q0.y,q0.z,q0.w,q1.x,q1.y,q1.z,q1.w};
      f16x8 hv, lv;
      #pragma unroll
      for (int i = 0; i < 8; ++i) {
        _Float16 h = (_Float16)vv[i];
        hv[i] = h;
        lv[i] = (_Float16)(vv[i] - (float)h);
        f2 = fmaf(vv[i], vv[i], f2);
      }
      fqh[s] = hv; fql[s] = lv;
    }
    // distance GEMM: 4 code-tiles x 2 k-steps x 3 split
    f32x4 dacc[4];
    #pragma unroll
    for (int t = 0; t < 4; ++t) dacc[t] = (f32x4){0.f,0.f,0.f,0.f};
    #pragma unroll
    for (int t = 0; t < 4; ++t)
      #pragma unroll
      for (int s = 0; s < 2; ++s) {
        dacc[t] = __builtin_amdgcn_mfma_f32_16x16x32_f16(Eah[t][s], fqh[s], dacc[t], 0, 0, 0);
        dacc[t] = __builtin_amdgcn_mfma_f32_16x16x32_f16(Eah[t][s], fql[s], dacc[t], 0, 0, 0);
        dacc[t] = __builtin_amdgcn_mfma_f32_16x16x32_f16(Eal[t][s], fqh[s], dacc[t], 0, 0, 0);
      }
    // per-lane top-2 over its 16 codes
    float d1 = 1e38f, d2 = 1e38f; int idx = 0;
    #pragma unroll
    for (int t = 0; t < 4; ++t)
      #pragma unroll
      for (int r = 0; r < 4; ++r) {
        int c = t*16 + g*4 + r;
        float d = fmaf(-2.f, dacc[t][r], e2l[t][r]);
        if (d < d1) { d2 = d1; d1 = d; idx = c; }
        else if (d < d2) d2 = d;
      }
    // merge across g-groups (xor 16, 32); ties -> smaller index, margin<=0 -> rescue
    #pragma unroll
    for (int off = 16; off <= 32; off <<= 1) {
      float od1 = __shfl_xor(d1, off), od2 = __shfl_xor(d2, off);
      int   oi  = __shfl_xor(idx, off);
      float of2 = __shfl_xor(f2, off);
      f2 += of2;
      if (od1 < d1 || (od1 == d1 && oi < idx)) {
        d2 = fminf(d1, od2); d1 = od1; idx = oi;
      } else {
        d2 = fminf(d2, od1);
      }
    }
    // exact fp64 rescue for near-ties (wave-cooperative, rare)
    bool valid = tok < NM;
    bool exact = false;
    u64 flags = __ballot(g == 0 && valid && (d2 - d1) < 1e-3f);
    while (flags) {
      int src = __ffsll(flags) - 1;        // src in 0..15
      flags &= flags - 1;
      int mrow = 1 + nt*16 + src;
      const float* xrow = x + (size_t)(b_*197 + mrow)*768;
      const float* wrow = qkv_w + (size_t)(which*768 + h_*64 + lane)*768;
      double qd = 0.0;
      for (int c = 0; c < 768; ++c) qd = fma((double)xrow[c], (double)wrow[c], qd);
      double bb = 1e300; int bi = 0;
      for (int kk = 0; kk < KCB; ++kk) {
        double df = qd - (double)El[kk*66 + lane];
        double sq = df*df;
        #pragma unroll
        for (int off = 32; off > 0; off >>= 1) sq += __shfl_xor(sq, off);
        if (sq < bb) { bb = sq; bi = kk; }
      }
      if (ln == src) { idx = bi; d1 = (float)bb; exact = true; }
    }
    if (g == 0 && valid) {
      idxb[tok] = idx;
      msum += exact ? d1 : (d1 + f2);
    }
  }
  __syncthreads();

  // write quantized rows (f16 of chosen codebook vectors)
  for (int idx = tid; idx < NM*64; idx += 256) {
    int mm = idx >> 6, i = idx & 63;
    dst[base + (size_t)(mm+1)*64 + i] = f2h(El[idxb[mm]*66 + i]);
  }

  // MSE partial reduce (msum lives on lanes 0..15 of each wave)
  #pragma unroll
  for (int off = 8; off > 0; off >>= 1) msum += __shfl_down(msum, off);
  if (lane == 0) wred[w] = msum;
  __syncthreads();
  if (tid == 0) pq[which*768 + bh] = wred[0]+wred[1]+wred[2]+wred[3];
}

// ---------------- fused attention via MFMA: S^T = K*Q^T, online 2-pass, PV fused ----------
__global__ __launch_bounds__(256)
void fused_attn_mfma(const float* __restrict__ qbuf, const float* __restrict__ kbuf,
                     const u16* __restrict__ cq, const u16* __restrict__ ck,
                     const u16* __restrict__ vb,
                     u16* __restrict__ aoh, u16* __restrict__ aol,
                     float* __restrict__ pkl)
{
  __shared__ __align__(16) u16 Kf[200*64];    // XOR-swizzled rows (slot^=row&7)
  __shared__ __align__(16) u16 CKf[200*64];
  __shared__ __align__(16) u16 Vt[64*212];    // V transposed [d][m], stride 212
  __shared__ float wred[4];
  const int tid = threadIdx.x;
  const int bh = blockIdx.x;
  const int b_ = bh / 12, h_ = bh - b_*12;
  const size_t base = (size_t)bh * (197*64);
  const u32* ck32 = (const u32*)ck;
  const u32* vb32 = (const u32*)vb;
  const size_t base2 = base >> 1;

  for (int idx = tid; idx < 197*32; idx += 256) {
    int m = idx >> 5, j = idx & 31;
    int dsti = m*32 + (((j >> 2) ^ (m & 7)) << 2) + (j & 3);
    float2 kv = *(const float2*)(kbuf + base + 2*idx);
    ((u32*)Kf)[dsti] = packh2(kv.x, kv.y);
    ((u32*)CKf)[dsti] = ck32[base2 + idx];
    u32 v2 = vb32[base2 + idx];
    Vt[(2*j)*212 + m]   = (u16)(v2 & 0xffff);
    Vt[(2*j+1)*212 + m] = (u16)(v2 >> 16);
  }
  for (int idx = tid; idx < 96; idx += 256) {
    int m = 197 + (idx >> 5), j = idx & 31;
    int dsti = m*32 + (((j >> 2) ^ (m & 7)) << 2) + (j & 3);
    ((u32*)Kf)[dsti] = 0; ((u32*)CKf)[dsti] = 0;
  }
  for (int idx = tid; idx < 64*15; idx += 256) {
    int d = idx / 15, mc = 197 + idx % 15;
    Vt[d*212 + mc] = 0;
  }
  __syncthreads();

  const int lane = tid & 63, w = tid >> 6;
  const int ln = lane & 15, g = lane >> 4;
  float klacc = 0.f;

  for (int nt = w; nt < 13; nt += 4) {
    const int n0 = nt*16;
    const int nb = n0 + ln;
    const float* qrow = qbuf + base + (size_t)nb*64;
    f16x8 fq[2], fcq[2];
    #pragma unroll
    for (int s = 0; s < 2; ++s) {
      float4 q0 = *(const float4*)(qrow + s*32 + g*8);
      float4 q1 = *(const float4*)(qrow + s*32 + g*8 + 4);
      fq[s] = (f16x8){(_Float16)q0.x,(_Float16)q0.y,(_Float16)q0.z,(_Float16)q0.w,
                      (_Float16)q1.x,(_Float16)q1.y,(_Float16)q1.z,(_Float16)q1.w};
      uint4 cu = *(const uint4*)(cq + base + (size_t)nb*64 + s*32 + g*8);
      *(uint4*)&fcq[s] = cu;
    }

    float Ma = -3e38f, Mq = -3e38f;
    for (int t = 0; t < 13; ++t) {
      int mrow = t*16 + ln; if (mrow > 199) mrow = 199;
      const char* kb8 = (const char*)Kf + mrow*128;
      const char* cb8 = (const char*)CKf + mrow*128;
      int sw = (mrow & 7) << 4;
      f32x4 sa = (f32x4){0.f,0.f,0.f,0.f}, sq = (f32x4){0.f,0.f,0.f,0.f};
      sa = __builtin_amdgcn_mfma_f32_16x16x32_f16(*(const f16x8*)(kb8 + (( g     <<4) ^ sw)), fq[0], sa, 0,0,0);
      sa = __builtin_amdgcn_mfma_f32_16x16x32_f16(*(const f16x8*)(kb8 + (((4+g)<<4) ^ sw)), fq[1], sa, 0,0,0);
      sq = __builtin_amdgcn_mfma_f32_16x16x32_f16(*(const f16x8*)(cb8 + (( g     <<4) ^ sw)), fcq[0], sq, 0,0,0);
      sq = __builtin_amdgcn_mfma_f32_16x16x32_f16(*(const f16x8*)(cb8 + (((4+g)<<4) ^ sw)), fcq[1], sq, 0,0,0);
      int mbase = t*16 + g*4;
      #pragma unroll
      for (int r = 0; r < 4; ++r) {
        bool v = (mbase + r) < 197;
        Ma = fmaxf(Ma, v ? sa[r] : -3e38f);
        Mq = fmaxf(Mq, v ? sq[r] : -3e38f);
      }
    }
    Ma = fmaxf(Ma, __shfl_xor(Ma, 16)); Ma = fmaxf(Ma, __shfl_xor(Ma, 32));
    Mq = fmaxf(Mq, __shfl_xor(Mq, 16)); Mq = fmaxf(Mq, __shfl_xor(Mq, 32));

    const float Mla = Ma * 0.125f, Mlq = Mq * 0.125f;
    float aS = 0.f, aT = 0.f, qS = 0.f, cross = 0.f;
    f32x4 ov[4];
    #pragma unroll
    for (int dt = 0; dt < 4; ++dt) ov[dt] = (f32x4){0.f,0.f,0.f,0.f};
    for (int t = 0; t < 13; ++t) {
      int mrow = t*16 + ln; if (mrow > 199) mrow = 199;
      const char* kb8 = (const char*)Kf + mrow*128;
      const char* cb8 = (const char*)CKf + mrow*128;
      int sw = (mrow & 7) << 4;
      f32x4 sa = (f32x4){0.f,0.f,0.f,0.f}, sq = (f32x4){0.f,0.f,0.f,0.f};
      sa = __builtin_amdgcn_mfma_f32_16x16x32_f16(*(const f16x8*)(kb8 + (( g     <<4) ^ sw)), fq[0], sa, 0,0,0);
      sa = __builtin_amdgcn_mfma_f32_16x16x32_f16(*(const f16x8*)(kb8 + (((4+g)<<4) ^ sw)), fq[1], sa, 0,0,0);
      sq = __builtin_amdgcn_mfma_f32_16x16x32_f16(*(const f16x8*)(cb8 + (( g     <<4) ^ sw)), fcq[0], sq, 0,0,0);
      sq = __builtin_amdgcn_mfma_f32_16x16x32_f16(*(const f16x8*)(cb8 + (((4+g)<<4) ^ sw)), fcq[1], sq, 0,0,0);
      int mbase = t*16 + g*4;
      float eqv[4];
      #pragma unroll
      for (int r = 0; r < 4; ++r) {
        bool v = (mbase + r) < 197;
        float ea = v ? __expf(fmaf(sa[r], 0.125f, -Mla)) : 0.f;
        float eq = v ? __expf(fmaf(sq[r], 0.125f, -Mlq)) : 0.f;
        aS += ea;
        aT = fmaf(ea, sa[r], aT);
        qS += eq;
        cross = fmaf(ea, eq, cross);
        eqv[r] = eq;
      }
      f16x4 qaf = {(_Float16)eqv[0], (_Float16)eqv[1], (_Float16)eqv[2], (_Float16)eqv[3]};
      #pragma unroll
      for (int dt = 0; dt < 4; ++dt) {
        f16x4 bv = *(const f16x4*)(Vt + (dt*16 + ln)*212 + t*16 + g*4);
        ov[dt] = __builtin_amdgcn_mfma_f32_16x16x16f16(qaf, bv, ov[dt], 0, 0, 0);
      }
    }
    aS += __shfl_xor(aS, 16); aS += __shfl_xor(aS, 32);
    aT += __shfl_xor(aT, 16); aT += __shfl_xor(aT, 32);
    qS += __shfl_xor(qS, 16); qS += __shfl_xor(qS, 32);
    cross += __shfl_xor(cross, 16); cross += __shfl_xor(cross, 32);

    if (g == 0 && nb < 197) {
      float rowkl = 0.125f*(aT/aS) - Mla - __logf(aS) - cross/(aS*qS);
      klacc += rowkl;
    }
    #pragma unroll
    for (int r = 0; r < 4; ++r) {
      int nl = g*4 + r;
      int nglob = n0 + nl;
      if (nglob >= 197) continue;
      float qSn = __shfl(qS, nl);
      float inv = __frcp_rn(qSn);
      size_t obase = ((size_t)(b_*197 + nglob))*768 + h_*64;
      #pragma unroll
      for (int dt = 0; dt < 4; ++dt) {
        float val = ov[dt][r] * inv;
        aoh[obase + dt*16 + ln] = f2h(val);
        aol[obase + dt*16 + ln] = f2h(hres(val));
      }
    }
  }

  #pragma unroll
  for (int off = 32; off > 0; off >>= 1) klacc += __shfl_down(klacc, off);
  if (lane == 0) wred[w] = klacc;
  __syncthreads();
  if (tid == 0) pkl[bh] = wred[0] + wred[1] + wred[2] + wred[3];
}

// ---------------- deterministic loss finalize ----------------
__global__ __launch_bounds__(256)
void finalize_kernel(const float* __restrict__ pq, const float* __restrict__ pkl,
                     float* __restrict__ dout)
{
  __shared__ double red[256];
  const int tid = threadIdx.x;
  double s0 = 0.0, s1 = 0.0;
  for (int i = tid; i < 1536; i += 256) s0 += (double)pq[i];
  for (int i = tid; i < 768; i += 256) s1 += (double)pkl[i];
  red[tid] = s0; __syncthreads();
  for (int off = 128; off > 0; off >>= 1) { if (tid < off) red[tid] += red[tid+off]; __syncthreads(); }
  double mse = red[0];
  __syncthreads();
  red[tid] = s1; __syncthreads();
  for (int off = 128; off > 0; off >>= 1) { if (tid < off) red[tid] += red[tid+off]; __syncthreads(); }
  double kl = red[0];
  if (tid == 0) dout[SZ] = (float)(mse / 9633792.0 + kl / 29805312.0);
}

extern "C" void kernel_launch(void* const* d_in, const int* in_sizes, int n_in,
                              void* d_out, int out_size, void* d_ws, size_t ws_size,
                              hipStream_t stream)
{
  const float* x      = (const float*)d_in[0];
  const float* qkv_w  = (const float*)d_in[1];
  const float* proj_w = (const float*)d_in[2];
  const float* proj_b = (const float*)d_in[3];
  const float* qe     = (const float*)d_in[4];
  const float* ke     = (const float*)d_in[5];
  float* out = (float*)d_out;

  float* ws  = (float*)d_ws;
  float* qb_ = ws;                       // SZ fp32
  float* kb_ = ws + SZ;                  // SZ fp32
  u16*   vb_ = (u16*)(ws + 2*SZ);        // SZ f16
  u16*   cq_ = vb_ + SZ;                 // SZ f16
  u16*   ck_ = cq_ + SZ;                 // SZ f16
  u16*   xh_ = ck_ + SZ;                 // SZ f16
  u16*   xl_ = xh_ + SZ;                 // SZ f16
  u16*   aoh_= xl_ + SZ;                 // SZ f16
  u16*   aol_= aoh_ + SZ;                // SZ f16
  u16*   wh_ = aol_ + SZ;                // WQKV f16
  u16*   wl_ = wh_ + WQKV;
  u16*   ph_ = wl_ + WQKV;               // WPRJ f16
  u16*   pl_ = ph_ + WPRJ;
  float* pq_ = (float*)(pl_ + WPRJ);     // 1536
  float* pkl_= pq_ + 1536;               // 768

  dim3 blk(256);
  split_kernel<<<dim3((int)(SZ/4/256)),   blk, 0, stream>>>(x, xh_, xl_, (int)(SZ/4));
  split_kernel<<<dim3((int)(WQKV/4/256)), blk, 0, stream>>>(qkv_w, wh_, wl_, (int)(WQKV/4));
  split_kernel<<<dim3((int)(WPRJ/4/256)), blk, 0, stream>>>(proj_w, ph_, pl_, (int)(WPRJ/4));
  gemm_mfma<0><<<dim3(99, 18), blk, 0, stream>>>(xh_, xl_, wh_, wl_, qb_, kb_, vb_, nullptr, nullptr);
  quant_mfma<<<dim3(768, 2), blk, 0, stream>>>(x, qkv_w, qb_, kb_, qe, ke, cq_, ck_, pq_);
  fused_attn_mfma<<<dim3(768), blk, 0, stream>>>(qb_, kb_, cq_, ck_, vb_, aoh_, aol_, pkl_);
  gemm_mfma<1><<<dim3(99, 6), blk, 0, stream>>>(aoh_, aol_, ph_, pl_, nullptr, nullptr, nullptr, proj_b, out);
  finalize_kernel<<<dim3(1), blk, 0, stream>>>(pq_, pkl_, out);
}

// Round 6
// 400.622 us; speedup vs baseline: 5.4684x; 1.1621x over previous
//
#include <hip/hip_runtime.h>
#include <math.h>

#define NB 64
#define NN 197
#define NC 768
#define NH 12
#define ND 64
#define KCB 50
#define NM (NN-1)                    // 196
#define BNROWS (NB*NN)               // 12608
#define SZ ((size_t)NB*NH*NN*ND)     // 9,682,944
#define WQKV ((size_t)2304*768)      // 1,769,472
#define WPRJ ((size_t)768*768)       // 589,824

typedef unsigned short u16;
typedef unsigned int u32;
typedef unsigned long long u64;
typedef _Float16 h2 __attribute__((ext_vector_type(2)));
typedef _Float16 f16x4 __attribute__((ext_vector_type(4)));
typedef _Float16 f16x8 __attribute__((ext_vector_type(8)));
typedef float f32x4 __attribute__((ext_vector_type(4)));

#define GLOAD16(gp, lp) __builtin_amdgcn_global_load_lds( \
    (const __attribute__((address_space(1))) void*)(gp),  \
    (__attribute__((address_space(3))) void*)(lp), 16, 0, 0)

__device__ __forceinline__ u16 f2h(float x) {
  _Float16 h = (_Float16)x;
  return *(u16*)&h;
}
__device__ __forceinline__ u32 packh2(float a, float b) {
  h2 v = { (_Float16)a, (_Float16)b };
  return *(u32*)&v;
}

// ---------------- split fp32 -> f16 hi (+ optional lo) planes ----------------
template<bool LO>
__global__ __launch_bounds__(256)
void split_kernel(const float* __restrict__ src, u16* __restrict__ hi,
                  u16* __restrict__ lo, int n4)
{
  int i = blockIdx.x*256 + threadIdx.x;
  if (i >= n4) return;
  float4 v = ((const float4*)src)[i];
  _Float16 h0 = (_Float16)v.x, h1 = (_Float16)v.y, h2_ = (_Float16)v.z, h3 = (_Float16)v.w;
  uint2 hv = make_uint2((u32)*(u16*)&h0 | ((u32)*(u16*)&h1 << 16),
                        (u32)*(u16*)&h2_ | ((u32)*(u16*)&h3 << 16));
  ((uint2*)hi)[i] = hv;
  if constexpr (LO) {
    _Float16 l0 = (_Float16)(v.x - (float)h0), l1 = (_Float16)(v.y - (float)h1);
    _Float16 l2 = (_Float16)(v.z - (float)h2_), l3 = (_Float16)(v.w - (float)h3);
    uint2 lv = make_uint2((u32)*(u16*)&l0 | ((u32)*(u16*)&l1 << 16),
                          (u32)*(u16*)&l2 | ((u32)*(u16*)&l3 << 16));
    ((uint2*)lo)[i] = lv;
  }
}

// ---------------- MFMA GEMM, f16, C[r,o] = sum_c A[r,c]*W[o,c] ----------------
// MODE 0: qkv (W 2304 rows) -> scatter q/k fp32 (split-3), v f16 (hi-only blocks)
// MODE 1: proj (W 768 rows) -> d_out + bias, hi-only
// planes: 0=Ah, 1=Wh, 2=Al, 3=Wl
template<int MODE>
__global__ __launch_bounds__(256)
void gemm_mfma(const u16* __restrict__ Ah, const u16* __restrict__ Al,
               const u16* __restrict__ Wh, const u16* __restrict__ Wl,
               float* __restrict__ qb_, float* __restrict__ kb_, u16* __restrict__ vb_,
               const float* __restrict__ bias, float* __restrict__ dout)
{
  constexpr int NPL = (MODE == 1) ? 2 : 4;
  __shared__ u16 lds[2][NPL][4096];   // [buf][plane][128 rows x 32 f16]
  const int tid = threadIdx.x;
  const int lane = tid & 63, w = tid >> 6;
  const int wm = w >> 1, wn = w & 1;
  const int row0 = blockIdx.x * 128, col0 = blockIdx.y * 128;
  const bool dolo = (MODE == 0) && (col0 < 1536);   // q/k need split-3; v hi-only

  f32x4 acc[4][4];
  #pragma unroll
  for (int mi = 0; mi < 4; ++mi)
    #pragma unroll
    for (int ni = 0; ni < 4; ++ni) acc[mi][ni] = (f32x4){0.f, 0.f, 0.f, 0.f};

  auto stage = [&](int buf, int kt) {
    const int c0 = kt * 32;
    #pragma unroll
    for (int j = 0; j < 2; ++j) {
      const int r0 = w*32 + j*16;
      const int lrow = r0 + (lane >> 2);
      const int slot = (lane & 3) ^ (lrow & 3);
      int ar = row0 + lrow; if (ar > BNROWS-1) ar = BNROWS-1;
      const size_t ga = (size_t)ar * 768 + c0 + slot*8;
      const size_t gb = (size_t)(col0 + lrow) * 768 + c0 + slot*8;
      GLOAD16(Ah + ga, &lds[buf][0][r0*32]);
      GLOAD16(Wh + gb, &lds[buf][1][r0*32]);
      if constexpr (MODE == 0) {
        if (dolo) {
          GLOAD16(Al + ga, &lds[buf][2][r0*32]);
          GLOAD16(Wl + gb, &lds[buf][3][r0*32]);
        }
      }
    }
  };

  auto compute = [&](int buf) {
    f16x8 ah[4], bh[4];
    const int g = lane >> 4;
    int offa[4], offb[4];
    #pragma unroll
    for (int mi = 0; mi < 4; ++mi) {
      int arow = wm*64 + mi*16 + (lane & 15);
      offa[mi] = arow*32 + ((g ^ (arow & 3)) << 3);
      ah[mi] = *(const f16x8*)&lds[buf][0][offa[mi]];
    }
    #pragma unroll
    for (int ni = 0; ni < 4; ++ni) {
      int brow = wn*64 + ni*16 + (lane & 15);
      offb[ni] = brow*32 + ((g ^ (brow & 3)) << 3);
      bh[ni] = *(const f16x8*)&lds[buf][1][offb[ni]];
    }
    #pragma unroll
    for (int mi = 0; mi < 4; ++mi)
      #pragma unroll
      for (int ni = 0; ni < 4; ++ni)
        acc[mi][ni] = __builtin_amdgcn_mfma_f32_16x16x32_f16(ah[mi], bh[ni], acc[mi][ni], 0, 0, 0);
    if constexpr (MODE == 0) {
      if (dolo) {
        f16x8 al[4], bl[4];
        #pragma unroll
        for (int mi = 0; mi < 4; ++mi) al[mi] = *(const f16x8*)&lds[buf][2][offa[mi]];
        #pragma unroll
        for (int ni = 0; ni < 4; ++ni) bl[ni] = *(const f16x8*)&lds[buf][3][offb[ni]];
        #pragma unroll
        for (int mi = 0; mi < 4; ++mi)
          #pragma unroll
          for (int ni = 0; ni < 4; ++ni) {
            acc[mi][ni] = __builtin_amdgcn_mfma_f32_16x16x32_f16(ah[mi], bl[ni], acc[mi][ni], 0, 0, 0);
            acc[mi][ni] = __builtin_amdgcn_mfma_f32_16x16x32_f16(al[mi], bh[ni], acc[mi][ni], 0, 0, 0);
          }
      }
    }
  };

  stage(0, 0);
  asm volatile("s_waitcnt vmcnt(0)" ::: "memory");
  __syncthreads();
  int cur = 0;
  for (int kt = 0; kt < 24; ++kt) {
    if (kt < 23) stage(cur ^ 1, kt + 1);
    compute(cur);
    asm volatile("s_waitcnt vmcnt(0)" ::: "memory");
    __syncthreads();
    cur ^= 1;
  }

  float* biasl = nullptr;
  if constexpr (MODE == 1) {
    biasl = (float*)&lds[0][0][0];
    if (tid < 128) biasl[tid] = bias[col0 + tid];
    __syncthreads();
  }
  #pragma unroll
  for (int mi = 0; mi < 4; ++mi) {
    #pragma unroll
    for (int t = 0; t < 4; ++t) {
      int r = row0 + wm*64 + mi*16 + (lane >> 4)*4 + t;
      if (r >= BNROWS) continue;
      if constexpr (MODE == 0) {
        int b_ = r / 197, n_ = r - b_*197;
        #pragma unroll
        for (int ni = 0; ni < 4; ++ni) {
          int o = col0 + wn*64 + ni*16 + (lane & 15);
          float val = acc[mi][ni][t];
          int tq = o / 768, rem = o - tq*768;
          int hh = rem >> 6, dd = rem & 63;
          size_t dst = ((size_t)(b_*12 + hh)*197 + n_)*64 + dd;
          if (tq == 0)      qb_[dst] = val;
          else if (tq == 1) kb_[dst] = val;
          else              vb_[dst] = f2h(val);
        }
      } else {
        #pragma unroll
        for (int ni = 0; ni < 4; ++ni) {
          int o = col0 + wn*64 + ni*16 + (lane & 15);
          dout[(size_t)r*768 + o] = acc[mi][ni][t] + biasl[o - col0];
        }
      }
    }
  }
}

// ---------------- Quantize via MFMA distance GEMM + fp64 rescue for near-ties ----------
__global__ __launch_bounds__(256)
void quant_mfma(const float* __restrict__ x, const float* __restrict__ qkv_w,
                const float* __restrict__ qbuf, const float* __restrict__ kbuf,
                const float* __restrict__ qe, const float* __restrict__ ke,
                u16* __restrict__ cq, u16* __restrict__ ck, float* __restrict__ pq)
{
  __shared__ __align__(16) float El[KCB*66];    // codebook fp32 (pad 66)
  __shared__ __align__(16) u16 Ehi[64*64];      // codebook f16 hi (rows 50..63 zero)
  __shared__ __align__(16) u16 Elo[64*64];      // codebook f16 lo
  __shared__ double e2d[KCB];
  __shared__ int idxb[NM];
  __shared__ float wred[4];
  const int tid = threadIdx.x;
  const int bh = blockIdx.x;
  const int which = blockIdx.y;
  const int b_ = bh / 12, h_ = bh - b_*12;
  const float* feat = which ? kbuf : qbuf;
  const float* emb  = which ? ke : qe;
  u16* dst = which ? ck : cq;
  const size_t base = (size_t)bh * (197*64);
  const int lane = tid & 63, w = tid >> 6;
  const int ln = lane & 15, g = lane >> 4;

  for (int idx = tid; idx < KCB*64; idx += 256) {
    int kk = idx >> 6, i = idx & 63;
    float v = emb[h_*(KCB*64) + idx];
    El[kk*66 + i] = v;
    _Float16 hv = (_Float16)v;
    Ehi[idx] = *(u16*)&hv;
    _Float16 lv = (_Float16)(v - (float)hv);
    Elo[idx] = *(u16*)&lv;
  }
  for (int idx = tid; idx < 14*64; idx += 256) {
    Ehi[KCB*64 + idx] = 0; Elo[KCB*64 + idx] = 0;
  }
  if (tid >= 64 && tid < 128) {
    int i = tid - 64;
    dst[base + i] = f2h(feat[base + i]);
  }
  __syncthreads();
  if (tid < KCB) {
    double s = 0.0;
    for (int i = 0; i < 64; ++i) { double e = (double)El[tid*66 + i]; s += e*e; }
    e2d[tid] = s;
  }
  __syncthreads();

  f16x8 Eah[4][2], Eal[4][2];
  float e2l[4][4];
  #pragma unroll
  for (int t = 0; t < 4; ++t) {
    #pragma unroll
    for (int s = 0; s < 2; ++s) {
      int off = (t*16 + ln)*64 + s*32 + g*8;
      Eah[t][s] = *(const f16x8*)&Ehi[off];
      Eal[t][s] = *(const f16x8*)&Elo[off];
    }
    #pragma unroll
    for (int r = 0; r < 4; ++r) {
      int c = t*16 + g*4 + r;
      e2l[t][r] = (c < KCB) ? (float)e2d[c] : 1e30f;
    }
  }

  float msum = 0.f;
  for (int nt = w; nt < 13; nt += 4) {
    int tok = nt*16 + ln;
    int tokc = tok < NM ? tok : NM-1;
    const float* frow = feat + base + (size_t)(tokc+1)*64;
    f16x8 fqh[2], fql[2];
    float f2 = 0.f;
    #pragma unroll
    for (int s = 0; s < 2; ++s) {
      float4 q0 = *(const float4*)(frow + s*32 + g*8);
      float4 q1 = *(const float4*)(frow + s*32 + g*8 + 4);
      float vv[8] = {q0.x,q0.y,q0.z,q0.w,q1.x,q1.y,q1.z,q1.w};
      f16x8 hv, lv;
      #pragma unroll
      for (int i = 0; i < 8; ++i) {
        _Float16 h = (_Float16)vv[i];
        hv[i] = h;
        lv[i] = (_Float16)(vv[i] - (float)h);
        f2 = fmaf(vv[i], vv[i], f2);
      }
      fqh[s] = hv; fql[s] = lv;
    }
    f32x4 dacc[4];
    #pragma unroll
    for (int t = 0; t < 4; ++t) dacc[t] = (f32x4){0.f,0.f,0.f,0.f};
    #pragma unroll
    for (int t = 0; t < 4; ++t)
      #pragma unroll
      for (int s = 0; s < 2; ++s) {
        dacc[t] = __builtin_amdgcn_mfma_f32_16x16x32_f16(Eah[t][s], fqh[s], dacc[t], 0, 0, 0);
        dacc[t] = __builtin_amdgcn_mfma_f32_16x16x32_f16(Eah[t][s], fql[s], dacc[t], 0, 0, 0);
        dacc[t] = __builtin_amdgcn_mfma_f32_16x16x32_f16(Eal[t][s], fqh[s], dacc[t], 0, 0, 0);
      }
    float d1 = 1e38f, d2 = 1e38f; int idx = 0;
    #pragma unroll
    for (int t = 0; t < 4; ++t)
      #pragma unroll
      for (int r = 0; r < 4; ++r) {
        int c = t*16 + g*4 + r;
        float d = fmaf(-2.f, dacc[t][r], e2l[t][r]);
        if (d < d1) { d2 = d1; d1 = d; idx = c; }
        else if (d < d2) d2 = d;
      }
    #pragma unroll
    for (int off = 16; off <= 32; off <<= 1) {
      float od1 = __shfl_xor(d1, off), od2 = __shfl_xor(d2, off);
      int   oi  = __shfl_xor(idx, off);
      float of2 = __shfl_xor(f2, off);
      f2 += of2;
      if (od1 < d1 || (od1 == d1 && oi < idx)) {
        d2 = fminf(d1, od2); d1 = od1; idx = oi;
      } else {
        d2 = fminf(d2, od1);
      }
    }
    bool valid = tok < NM;
    bool exact = false;
    u64 flags = __ballot(g == 0 && valid && (d2 - d1) < 1e-3f);
    while (flags) {
      int src = __ffsll(flags) - 1;
      flags &= flags - 1;
      int mrow = 1 + nt*16 + src;
      const float* xrow = x + (size_t)(b_*197 + mrow)*768;
      const float* wrow = qkv_w + (size_t)(which*768 + h_*64 + lane)*768;
      double qd = 0.0;
      for (int c = 0; c < 768; ++c) qd = fma((double)xrow[c], (double)wrow[c], qd);
      double bb = 1e300; int bi = 0;
      for (int kk = 0; kk < KCB; ++kk) {
        double df = qd - (double)El[kk*66 + lane];
        double sq = df*df;
        #pragma unroll
        for (int off = 32; off > 0; off >>= 1) sq += __shfl_xor(sq, off);
        if (sq < bb) { bb = sq; bi = kk; }
      }
      if (ln == src) { idx = bi; d1 = (float)bb; exact = true; }
    }
    if (g == 0 && valid) {
      idxb[tok] = idx;
      msum += exact ? d1 : (d1 + f2);
    }
  }
  __syncthreads();

  for (int idx = tid; idx < NM*64; idx += 256) {
    int mm = idx >> 6, i = idx & 63;
    dst[base + (size_t)(mm+1)*64 + i] = f2h(El[idxb[mm]*66 + i]);
  }

  #pragma unroll
  for (int off = 8; off > 0; off >>= 1) msum += __shfl_down(msum, off);
  if (lane == 0) wred[w] = msum;
  __syncthreads();
  if (tid == 0) pq[which*768 + bh] = wred[0]+wred[1]+wred[2]+wred[3];
}

// ---------------- fused attention via MFMA: S^T = K*Q^T, online 2-pass, PV fused ----------
__global__ __launch_bounds__(256)
void fused_attn_mfma(const float* __restrict__ qbuf, const float* __restrict__ kbuf,
                     const u16* __restrict__ cq, const u16* __restrict__ ck,
                     const u16* __restrict__ vb,
                     u16* __restrict__ aoh, float* __restrict__ pkl)
{
  __shared__ __align__(16) u16 Kf[200*64];    // XOR-swizzled rows (slot^=row&7)
  __shared__ __align__(16) u16 CKf[200*64];
  __shared__ __align__(16) u16 Vt[64*212];    // V transposed [d][m], stride 212
  __shared__ float wred[4];
  const int tid = threadIdx.x;
  const int bh = blockIdx.x;
  const int b_ = bh / 12, h_ = bh - b_*12;
  const size_t base = (size_t)bh * (197*64);
  const u32* ck32 = (const u32*)ck;
  const u32* vb32 = (const u32*)vb;
  const size_t base2 = base >> 1;

  for (int idx = tid; idx < 197*32; idx += 256) {
    int m = idx >> 5, j = idx & 31;
    int dsti = m*32 + (((j >> 2) ^ (m & 7)) << 2) + (j & 3);
    float2 kv = *(const float2*)(kbuf + base + 2*idx);
    ((u32*)Kf)[dsti] = packh2(kv.x, kv.y);
    ((u32*)CKf)[dsti] = ck32[base2 + idx];
    u32 v2 = vb32[base2 + idx];
    Vt[(2*j)*212 + m]   = (u16)(v2 & 0xffff);
    Vt[(2*j+1)*212 + m] = (u16)(v2 >> 16);
  }
  for (int idx = tid; idx < 96; idx += 256) {
    int m = 197 + (idx >> 5), j = idx & 31;
    int dsti = m*32 + (((j >> 2) ^ (m & 7)) << 2) + (j & 3);
    ((u32*)Kf)[dsti] = 0; ((u32*)CKf)[dsti] = 0;
  }
  for (int idx = tid; idx < 64*15; idx += 256) {
    int d = idx / 15, mc = 197 + idx % 15;
    Vt[d*212 + mc] = 0;
  }
  __syncthreads();

  const int lane = tid & 63, w = tid >> 6;
  const int ln = lane & 15, g = lane >> 4;
  float klacc = 0.f;

  for (int nt = w; nt < 13; nt += 4) {
    const int n0 = nt*16;
    const int nb = n0 + ln;
    const float* qrow = qbuf + base + (size_t)nb*64;
    f16x8 fq[2], fcq[2];
    #pragma unroll
    for (int s = 0; s < 2; ++s) {
      float4 q0 = *(const float4*)(qrow + s*32 + g*8);
      float4 q1 = *(const float4*)(qrow + s*32 + g*8 + 4);
      fq[s] = (f16x8){(_Float16)q0.x,(_Float16)q0.y,(_Float16)q0.z,(_Float16)q0.w,
                      (_Float16)q1.x,(_Float16)q1.y,(_Float16)q1.z,(_Float16)q1.w};
      uint4 cu = *(const uint4*)(cq + base + (size_t)nb*64 + s*32 + g*8);
      *(uint4*)&fcq[s] = cu;
    }

    float Ma = -3e38f, Mq = -3e38f;
    for (int t = 0; t < 13; ++t) {
      int mrow = t*16 + ln; if (mrow > 199) mrow = 199;
      const char* kb8 = (const char*)Kf + mrow*128;
      const char* cb8 = (const char*)CKf + mrow*128;
      int sw = (mrow & 7) << 4;
      f32x4 sa = (f32x4){0.f,0.f,0.f,0.f}, sq = (f32x4){0.f,0.f,0.f,0.f};
      sa = __builtin_amdgcn_mfma_f32_16x16x32_f16(*(const f16x8*)(kb8 + (( g     <<4) ^ sw)), fq[0], sa, 0,0,0);
      sa = __builtin_amdgcn_mfma_f32_16x16x32_f16(*(const f16x8*)(kb8 + (((4+g)<<4) ^ sw)), fq[1], sa, 0,0,0);
      sq = __builtin_amdgcn_mfma_f32_16x16x32_f16(*(const f16x8*)(cb8 + (( g     <<4) ^ sw)), fcq[0], sq, 0,0,0);
      sq = __builtin_amdgcn_mfma_f32_16x16x32_f16(*(const f16x8*)(cb8 + (((4+g)<<4) ^ sw)), fcq[1], sq, 0,0,0);
      int mbase = t*16 + g*4;
      #pragma unroll
      for (int r = 0; r < 4; ++r) {
        bool v = (mbase + r) < 197;
        Ma = fmaxf(Ma, v ? sa[r] : -3e38f);
        Mq = fmaxf(Mq, v ? sq[r] : -3e38f);
      }
    }
    Ma = fmaxf(Ma, __shfl_xor(Ma, 16)); Ma = fmaxf(Ma, __shfl_xor(Ma, 32));
    Mq = fmaxf(Mq, __shfl_xor(Mq, 16)); Mq = fmaxf(Mq, __shfl_xor(Mq, 32));

    const float Mla = Ma * 0.125f, Mlq = Mq * 0.125f;
    float aS = 0.f, aT = 0.f, qS = 0.f, cross = 0.f;
    f32x4 ov[4];
    #pragma unroll
    for (int dt = 0; dt < 4; ++dt) ov[dt] = (f32x4){0.f,0.f,0.f,0.f};
    for (int t = 0; t < 13; ++t) {
      int mrow = t*16 + ln; if (mrow > 199) mrow = 199;
      const char* kb8 = (const char*)Kf + mrow*128;
      const char* cb8 = (const char*)CKf + mrow*128;
      int sw = (mrow & 7) << 4;
      f32x4 sa = (f32x4){0.f,0.f,0.f,0.f}, sq = (f32x4){0.f,0.f,0.f,0.f};
      sa = __builtin_amdgcn_mfma_f32_16x16x32_f16(*(const f16x8*)(kb8 + (( g     <<4) ^ sw)), fq[0], sa, 0,0,0);
      sa = __builtin_amdgcn_mfma_f32_16x16x32_f16(*(const f16x8*)(kb8 + (((4+g)<<4) ^ sw)), fq[1], sa, 0,0,0);
      sq = __builtin_amdgcn_mfma_f32_16x16x32_f16(*(const f16x8*)(cb8 + (( g     <<4) ^ sw)), fcq[0], sq, 0,0,0);
      sq = __builtin_amdgcn_mfma_f32_16x16x32_f16(*(const f16x8*)(cb8 + (((4+g)<<4) ^ sw)), fcq[1], sq, 0,0,0);
      int mbase = t*16 + g*4;
      float eqv[4];
      #pragma unroll
      for (int r = 0; r < 4; ++r) {
        bool v = (mbase + r) < 197;
        float ea = v ? __expf(fmaf(sa[r], 0.125f, -Mla)) : 0.f;
        float eq = v ? __expf(fmaf(sq[r], 0.125f, -Mlq)) : 0.f;
        aS += ea;
        aT = fmaf(ea, sa[r], aT);
        qS += eq;
        cross = fmaf(ea, eq, cross);
        eqv[r] = eq;
      }
      f16x4 qaf = {(_Float16)eqv[0], (_Float16)eqv[1], (_Float16)eqv[2], (_Float16)eqv[3]};
      #pragma unroll
      for (int dt = 0; dt < 4; ++dt) {
        f16x4 bv = *(const f16x4*)(Vt + (dt*16 + ln)*212 + t*16 + g*4);
        ov[dt] = __builtin_amdgcn_mfma_f32_16x16x16f16(qaf, bv, ov[dt], 0, 0, 0);
      }
    }
    aS += __shfl_xor(aS, 16); aS += __shfl_xor(aS, 32);
    aT += __shfl_xor(aT, 16); aT += __shfl_xor(aT, 32);
    qS += __shfl_xor(qS, 16); qS += __shfl_xor(qS, 32);
    cross += __shfl_xor(cross, 16); cross += __shfl_xor(cross, 32);

    if (g == 0 && nb < 197) {
      float rowkl = 0.125f*(aT/aS) - Mla - __logf(aS) - cross/(aS*qS);
      klacc += rowkl;
    }
    #pragma unroll
    for (int r = 0; r < 4; ++r) {
      int nl = g*4 + r;
      int nglob = n0 + nl;
      if (nglob >= 197) continue;
      float qSn = __shfl(qS, nl);
      float inv = __frcp_rn(qSn);
      size_t obase = ((size_t)(b_*197 + nglob))*768 + h_*64;
      #pragma unroll
      for (int dt = 0; dt < 4; ++dt)
        aoh[obase + dt*16 + ln] = f2h(ov[dt][r] * inv);
    }
  }

  #pragma unroll
  for (int off = 32; off > 0; off >>= 1) klacc += __shfl_down(klacc, off);
  if (lane == 0) wred[w] = klacc;
  __syncthreads();
  if (tid == 0) pkl[bh] = wred[0] + wred[1] + wred[2] + wred[3];
}

// ---------------- deterministic loss finalize ----------------
__global__ __launch_bounds__(256)
void finalize_kernel(const float* __restrict__ pq, const float* __restrict__ pkl,
                     float* __restrict__ dout)
{
  __shared__ double red[256];
  const int tid = threadIdx.x;
  double s0 = 0.0, s1 = 0.0;
  for (int i = tid; i < 1536; i += 256) s0 += (double)pq[i];
  for (int i = tid; i < 768; i += 256) s1 += (double)pkl[i];
  red[tid] = s0; __syncthreads();
  for (int off = 128; off > 0; off >>= 1) { if (tid < off) red[tid] += red[tid+off]; __syncthreads(); }
  double mse = red[0];
  __syncthreads();
  red[tid] = s1; __syncthreads();
  for (int off = 128; off > 0; off >>= 1) { if (tid < off) red[tid] += red[tid+off]; __syncthreads(); }
  double kl = red[0];
  if (tid == 0) dout[SZ] = (float)(mse / 9633792.0 + kl / 29805312.0);
}

extern "C" void kernel_launch(void* const* d_in, const int* in_sizes, int n_in,
                              void* d_out, int out_size, void* d_ws, size_t ws_size,
                              hipStream_t stream)
{
  const float* x      = (const float*)d_in[0];
  const float* qkv_w  = (const float*)d_in[1];
  const float* proj_w = (const float*)d_in[2];
  const float* proj_b = (const float*)d_in[3];
  const float* qe     = (const float*)d_in[4];
  const float* ke     = (const float*)d_in[5];
  float* out = (float*)d_out;

  float* ws  = (float*)d_ws;
  float* qb_ = ws;                       // SZ fp32
  float* kb_ = ws + SZ;                  // SZ fp32
  u16*   vb_ = (u16*)(ws + 2*SZ);        // SZ f16
  u16*   cq_ = vb_ + SZ;                 // SZ f16
  u16*   ck_ = cq_ + SZ;                 // SZ f16
  u16*   xh_ = ck_ + SZ;                 // SZ f16
  u16*   xl_ = xh_ + SZ;                 // SZ f16
  u16*   aoh_= xl_ + SZ;                 // SZ f16
  u16*   wh_ = aoh_ + SZ;                // WQKV f16
  u16*   wl_ = wh_ + WQKV;
  u16*   ph_ = wl_ + WQKV;               // WPRJ f16
  float* pq_ = (float*)(ph_ + WPRJ);     // 1536
  float* pkl_= pq_ + 1536;               // 768

  dim3 blk(256);
  split_kernel<true><<<dim3((int)(SZ/4/256)),   blk, 0, stream>>>(x, xh_, xl_, (int)(SZ/4));
  split_kernel<true><<<dim3((int)(WQKV/4/256)), blk, 0, stream>>>(qkv_w, wh_, wl_, (int)(WQKV/4));
  split_kernel<false><<<dim3((int)(WPRJ/4/256)), blk, 0, stream>>>(proj_w, ph_, nullptr, (int)(WPRJ/4));
  gemm_mfma<0><<<dim3(99, 18), blk, 0, stream>>>(xh_, xl_, wh_, wl_, qb_, kb_, vb_, nullptr, nullptr);
  quant_mfma<<<dim3(768, 2), blk, 0, stream>>>(x, qkv_w, qb_, kb_, qe, ke, cq_, ck_, pq_);
  fused_attn_mfma<<<dim3(768), blk, 0, stream>>>(qb_, kb_, cq_, ck_, vb_, aoh_, pkl_);
  gemm_mfma<1><<<dim3(99, 6), blk, 0, stream>>>(aoh_, nullptr, ph_, nullptr, nullptr, nullptr, nullptr, proj_b, out);
  finalize_kernel<<<dim3(1), blk, 0, stream>>>(pq_, pkl_, out);
}